// Round 13
// baseline (111.630 us; speedup 1.0000x reference)
//
#include <hip/hip_runtime.h>

// y = convT3d(x, weight.sum(oc), stride=2, pad=2, k=5) + sum(bias); out = 6^3 stride-6 max.
// MFMA formulation (verified R6-R12, absmax 0.25): y[2m+t] = sum_{ic,abc} x[ic,m+1-abc]*w[ic,t+2abc]
// R13: ONE kernel, producer->consumer overlap. 400 blocks x 576 thr (3 blocks/CU by LDS+bounds
//   => all 400 co-resident, no deadlock). Producer: 1088 transpose slices (n-major) + 27 prep
//   units, signalled via agent-scope release atomics cnt[n]/cnt[16]. Consumer: spin (relaxed
//   poll + acquire fence) then R11 conv core verbatim. Counters zeroed by captured memset.

typedef short v8s __attribute__((ext_vector_type(8)));
typedef float v4f __attribute__((ext_vector_type(4)));
typedef unsigned short ushort_t;

#define CHSTR 16384
#define NSTRIDE (32*CHSTR)
#define Y_N 108000
#define Y_TOT (16*Y_N)
#define XSTR 24

#define XTN   665856u            // per-n xT: 18*34*34*32
#define PLANE_US 36992u          // 34*34*32
#define ROW_US 1088u             // 34*32
#define BT_BYTE_OFF 21307392u    // xT = 16*XTN*2 bytes
#define WSF_BYTE_OFF 21335040u   // +27*64*8*2
#define CNT_BYTE_OFF 21351488u   // +4097*4 rounded
#define NEED_FUSED (21351488u + 128u)

static __device__ __forceinline__ ushort_t f2bf(float f) {
  unsigned u = __builtin_bit_cast(unsigned, f);
  unsigned r = (u + 0x7FFFu + ((u >> 16) & 1u)) >> 16;
  return (ushort_t)r;
}

__global__ __launch_bounds__(576, 7) void fused_all(const float* __restrict__ x,
                                                    const float* __restrict__ wt,
                                                    const float* __restrict__ bias,
                                                    ushort_t* __restrict__ xT,
                                                    ushort_t* __restrict__ Btab,
                                                    float* __restrict__ wsf,
                                                    unsigned* __restrict__ cnt,
                                                    float* __restrict__ out) {
  __shared__ __align__(16) char smem[35328];
  int b = blockIdx.x, t = threadIdx.x;

  // ================= producer phase: up to 3 units =================
  float* lb = (float*)smem;                  // 2 x 1056 floats (transpose staging)
  for (int k = 0; k < 3; ++k) {
    int u;
    bool isprep = false;
    if (k == 0) {
      if (b < 373) u = b; else { isprep = true; u = b - 373; }   // prep FIRST (27 units)
    } else if (k == 1) {
      u = 373 + b;                            // 373..772
    } else {
      u = 773 + b;                            // 773..1087
      if (u >= 1088) break;
    }

    if (isprep) {
      // ---- Btab from raw w (verified R10/R12 prep_bw), abc = u
      if (t < 256) {
        int abc = u;
        int a = abc / 9, bb = (abc / 3) % 3, c = abc % 3;
        int half = t & 3;
        int l = t >> 2;
        int tt = l & 15, g = l >> 4;
        float v0 = 0.f, v1 = 0.f;
        if (tt < 8) {
          int td = tt & 1, th = (tt >> 1) & 1, tw = tt >> 2;
          int kd = td + 2 * a, kh = th + 2 * bb, kw = tw + 2 * c;
          if (kd < 5 && kh < 5 && kw < 5) {
            int off = kd * 25 + kh * 5 + kw;
            const float* wp0 = wt + (size_t)(8 * g + 2 * half) * 64 * 125 + off;
            const float* wp1 = wp0 + 64 * 125;
            float s0 = 0.f, s1 = 0.f;
#pragma unroll
            for (int oc = 0; oc < 64; ++oc) { s0 += wp0[oc * 125]; s1 += wp1[oc * 125]; }
            v0 = s0; v1 = s1;
          }
        }
        ((unsigned*)Btab)[(abc * 64 + l) * 4 + half] =
            (unsigned)f2bf(v0) | ((unsigned)f2bf(v1) << 16);
        if (abc == 0 && t == 0) {
          float bs = 0.f;
          for (int o = 0; o < 64; ++o) bs += bias[o];
          wsf[4096] = bs;
        }
      }
      __syncthreads();
      if (t == 0)
        __hip_atomic_fetch_add(&cnt[16], 1u, __ATOMIC_RELEASE, __HIP_MEMORY_SCOPE_AGENT);
      continue;
    }

    // ---- transpose slice u (verified R9 body; t<256 active, barriers all-thread)
    int hq = u & 3, dpad = (u >> 2) % 17, tn = u / 68;
    int h0 = 8 * hq;
    ushort_t* plane = xT + (size_t)(tn * 18 + dpad) * PLANE_US;
    int d = dpad - 1;

    if (d < 0) {                              // dpad==0 -> zero slice
      if (t < 256) {
        for (int r = 0; r < 8; ++r) {
          char* row = (char*)(plane + (size_t)(h0 + r) * ROW_US);
          for (int s = t; s < 136; s += 256)
            *(uint4*)(row + s * 16) = make_uint4(0, 0, 0, 0);
        }
      }
    } else {
      const float* xb = x + ((size_t)tn * 32 * 16 + d) * 1024;
      int ic = t >> 3, wq = t & 7;
      if (t < 256) {
        int h = h0 - 1;
        if (h >= 0) {
          float4 v = *(const float4*)&xb[(size_t)ic * 16384 + h * 32 + wq * 4];
          float* L = lb + ic * 33 + wq * 4;
          L[0] = v.x; L[1] = v.y; L[2] = v.z; L[3] = v.w;
        }
      }
      int pp = 0;
      for (int i = 0; i < 8; ++i) {
        __syncthreads();
        if (t < 256) {
          if (i + 1 < 8) {
            int h = h0 + i;
            if (h <= 31) {
              float4 v = *(const float4*)&xb[(size_t)ic * 16384 + h * 32 + wq * 4];
              float* L = lb + (pp ^ 1) * 1056 + ic * 33 + wq * 4;
              L[0] = v.x; L[1] = v.y; L[2] = v.z; L[3] = v.w;
            }
          }
          int h = h0 + i - 1;
          ushort_t* row = plane + (size_t)(h0 + i) * ROW_US;
          bool hv = (h >= 0 && h <= 31);
          const float* L = lb + pp * 1056;
          for (int s = t; s < 136; s += 256) {
            int wslot = s >> 2, q4 = s & 3;
            ushort_t o[8];
#pragma unroll
            for (int j = 0; j < 8; ++j) o[j] = 0;
            if (wslot >= 1 && wslot <= 32 && hv) {
              int w2 = wslot - 1;
#pragma unroll
              for (int j = 0; j < 8; ++j) o[j] = f2bf(L[(8 * q4 + j) * 33 + w2]);
            }
            uint4 pk;
            pk.x = (unsigned)o[0] | ((unsigned)o[1] << 16);
            pk.y = (unsigned)o[2] | ((unsigned)o[3] << 16);
            pk.z = (unsigned)o[4] | ((unsigned)o[5] << 16);
            pk.w = (unsigned)o[6] | ((unsigned)o[7] << 16);
            *(uint4*)(row + wslot * 32 + q4 * 8) = pk;
          }
        }
        pp ^= 1;
      }
    }
    __syncthreads();
    if (t == 0)
      __hip_atomic_fetch_add(&cnt[tn], 1u, __ATOMIC_RELEASE, __HIP_MEMORY_SCOPE_AGENT);
  }

  // ================= consumer phase: wait for deps =================
  int OH2 = b % 5, OD = (b / 5) % 5, n = b / 25;
  if (t == 0) {
    while (__hip_atomic_load(&cnt[16], __ATOMIC_RELAXED, __HIP_MEMORY_SCOPE_AGENT) < 27u)
      __builtin_amdgcn_s_sleep(16);
    while (__hip_atomic_load(&cnt[n], __ATOMIC_RELAXED, __HIP_MEMORY_SCOPE_AGENT) < 68u)
      __builtin_amdgcn_s_sleep(16);
  }
  __syncthreads();
  __builtin_amdgcn_fence(__ATOMIC_ACQUIRE, "agent");

  // ================= conv core (R11 verbatim, LDS overlay) =================
  ushort_t* As0 = (ushort_t*)smem;                 // 17408 B
  ushort_t* As1 = (ushort_t*)(smem + 17408);       // 17408 B
  float* ytile  = (float*)smem;                    // 18432 B (overlays, dead A-bufs)
  float* red    = (float*)(smem + 34816);          // 480 B

  int wv = t >> 6, l = t & 63;
  int mdl = wv / 3, mhp = wv % 3;
  int tt = l & 15, g = l >> 4;

  const ushort_t* xn = xT + (size_t)n * XTN;
  const ushort_t* slab0 = xn + ((size_t)(3 * OD) * 34 + 6 * OH2) * ROW_US;

  {
    uint4 v0 = *(const uint4*)(slab0 + (size_t)t * 8);
    uint4 v1;
    if (t < 512) v1 = *(const uint4*)(slab0 + (size_t)(t + 576) * 8);
    *(uint4*)&As0[t * 8] = v0;
    if (t < 512) *(uint4*)&As0[(t + 576) * 8] = v1;
  }
  __syncthreads();

  v4f acc[2][2];
#pragma unroll
  for (int m2 = 0; m2 < 2; ++m2)
#pragma unroll
    for (int wh = 0; wh < 2; ++wh) acc[m2][wh] = (v4f){0.f, 0.f, 0.f, 0.f};

  int lane_base = (2 * mhp) * ROW_US + tt * 32 + g * 8;

  for (int p = 0; p < 5; ++p) {
    uint4 v0, v1;
    if (p < 4) {
      const ushort_t* slab = slab0 + (size_t)(p + 1) * PLANE_US;
      v0 = *(const uint4*)(slab + (size_t)t * 8);
      if (t < 512) v1 = *(const uint4*)(slab + (size_t)(t + 576) * 8);
    }

    int a = mdl + 2 - p;
    if (0 <= a && a <= 2) {
      const ushort_t* Ab = (p & 1) ? As1 : As0;
      const ushort_t* Bg = Btab + ((size_t)(a * 9) * 64 + l) * 8;
#pragma unroll
      for (int c = 0; c < 3; ++c) {
        v8s bv0 = *(const v8s*)(Bg + (0 * 3 + c) * 512);
        v8s bv1 = *(const v8s*)(Bg + (1 * 3 + c) * 512);
        v8s bv2 = *(const v8s*)(Bg + (2 * 3 + c) * 512);
#pragma unroll
        for (int wh = 0; wh < 2; ++wh) {
          const ushort_t* ap = Ab + lane_base + (2 - c + 16 * wh) * 32;
          v8s a0 = *(const v8s*)(ap);
          v8s a1 = *(const v8s*)(ap + 1 * ROW_US);
          v8s a2 = *(const v8s*)(ap + 2 * ROW_US);
          v8s a3 = *(const v8s*)(ap + 3 * ROW_US);
          acc[0][wh] = __builtin_amdgcn_mfma_f32_16x16x32_bf16(a0, bv2, acc[0][wh], 0, 0, 0);
          acc[0][wh] = __builtin_amdgcn_mfma_f32_16x16x32_bf16(a1, bv1, acc[0][wh], 0, 0, 0);
          acc[0][wh] = __builtin_amdgcn_mfma_f32_16x16x32_bf16(a2, bv0, acc[0][wh], 0, 0, 0);
          acc[1][wh] = __builtin_amdgcn_mfma_f32_16x16x32_bf16(a1, bv2, acc[1][wh], 0, 0, 0);
          acc[1][wh] = __builtin_amdgcn_mfma_f32_16x16x32_bf16(a2, bv1, acc[1][wh], 0, 0, 0);
          acc[1][wh] = __builtin_amdgcn_mfma_f32_16x16x32_bf16(a3, bv0, acc[1][wh], 0, 0, 0);
        }
      }
    }

    if (p < 4) {
      ushort_t* dst = (p & 1) ? As0 : As1;
      *(uint4*)&dst[t * 8] = v0;
      if (t < 512) *(uint4*)&dst[(t + 576) * 8] = v1;
      __syncthreads();
    }
  }

  __syncthreads();
  if (tt < 8) {
    int td = tt & 1, th = (tt >> 1) & 1, tw = tt >> 2;
    int odl = 2 * mdl + td;
#pragma unroll
    for (int m2 = 0; m2 < 2; ++m2) {
      int ohl = 2 * (2 * mhp + m2) + th;
      float* yrow = &ytile[(odl * 12 + ohl) * 64];
#pragma unroll
      for (int wh = 0; wh < 2; ++wh)
#pragma unroll
        for (int i = 0; i < 4; ++i)
          yrow[2 * (16 * wh + 4 * g + i) + tw] = acc[m2][wh][i];
    }
  }
  __syncthreads();

  if (t < 120) {
    int OW = t % 10, p_oh = (t / 10) & 1, odl = t / 20;
    float m = -3.4e38f;
    for (int oh = 0; oh < 6; ++oh)
#pragma unroll
      for (int j = 0; j < 6; ++j)
        m = fmaxf(m, ytile[(odl * 12 + 6 * p_oh + oh) * 64 + 6 * OW + j]);
    red[t] = m;
  }
  __syncthreads();
  if (t < 20) {
    int OW = t % 10, p_oh = t / 10;
    float m = red[p_oh * 10 + OW];
#pragma unroll
    for (int odl = 1; odl < 6; ++odl) m = fmaxf(m, red[odl * 20 + p_oh * 10 + OW]);
    out[((n * 5 + OD) * 10 + (2 * OH2 + p_oh)) * 10 + OW] = m + wsf[4096];
  }
}

// ================= fallback: R5 verified fp32 path (tiny ws) ===========
__global__ __launch_bounds__(128) void prep2(const float* __restrict__ w,
                                             const float* __restrict__ bias,
                                             float* __restrict__ ws, int woff) {
  int i = blockIdx.x, t = threadIdx.x;
  if (t < 125) {
    const float* wp = w + (size_t)i * 64 * 125 + t;
    float v = 0.f;
#pragma unroll
    for (int o = 0; o < 64; ++o) v += wp[o * 125];
    ws[woff + i * 128 + t] = v;
  }
  if (i == 0 && t == 126) {
    float b = 0.f;
    for (int o = 0; o < 64; ++o) b += bias[o];
    ws[woff + 4096] = b;
  }
}

__global__ __launch_bounds__(256, 4) void conv_stage1(const float* __restrict__ x,
                                                      const float* __restrict__ ws,
                                                      float* part, int woff) {
  __shared__ __align__(16) float xs[170 * XSTR];
  int blk = blockIdx.x;
  int s0 = blk % 320;
  int wq = s0 & 1, hq = (s0 >> 1) & 1, dc = (s0 >> 2) % 5, n = s0 / 20;
  int t = threadIdx.x;
  int mw = t % 15, lmh = t / 15;
  int id_base = 3 * dc - 1, ih_base = 15 * hq - 1;
  int iwb = wq ? 12 : -4;
  int cb = mw + (wq ? 2 : 3);
  const float* xn = x + (size_t)n * NSTRIDE;
  const float* wsw = ws + woff;
  float acc[3][2][2][2] = {{{{0.f}}}};
  for (int phs = 0; phs < 16; ++phs) {
    for (int s = t; s < 1700; s += 256) {
      int c2 = s % 10, row = s / 10;
      int bh = row % 17, q = row / 17;
      int ad = q % 5, lic = q / 5;
      int id = id_base + ad, ih = ih_base + bh, iw = iwb + 2 * c2;
      float2 v = make_float2(0.f, 0.f);
      if ((id | ih | iw) >= 0)
        v = *(const float2*)&xn[(size_t)(phs * 2 + lic) * CHSTR + (id * 32 + ih) * 32 + iw];
      *(float2*)&xs[row * XSTR + 2 * c2] = v;
    }
    __syncthreads();
    if (t < 225) {
#pragma unroll
      for (int lic = 0; lic < 2; ++lic) {
        const float* wc = wsw + (size_t)(phs * 2 + lic) * 128;
        const float* xc = &xs[(lic * 85 + lmh) * XSTR + cb];
        float xv[5][3][3];
#pragma unroll
        for (int a = 0; a < 5; ++a)
#pragma unroll
          for (int b = 0; b < 3; ++b) {
            const float* xr = xc + (a * 17 + b) * XSTR;
            xv[a][b][0] = xr[0]; xv[a][b][1] = xr[1]; xv[a][b][2] = xr[2];
          }
#pragma unroll
        for (int kd = 0; kd < 5; ++kd) {
          constexpr int DT[5] = {0, 1, 0, 1, 0};
          constexpr int AOFF[5] = {2, 2, 1, 1, 0};
          const int dt = DT[kd], aoff = AOFF[kd];
          float wvv[25];
#pragma unroll
          for (int j = 0; j < 25; ++j) wvv[j] = wc[kd * 25 + j];
#pragma unroll
          for (int kh = 0; kh < 5; ++kh) {
            constexpr int HT[5] = {0, 1, 0, 1, 0};
            constexpr int BOFF[5] = {2, 2, 1, 1, 0};
            const int ht = HT[kh], boff = BOFF[kh];
#pragma unroll
            for (int m = 0; m < 3; ++m) {
              const float x0 = xv[m + aoff][boff][0];
              const float x1 = xv[m + aoff][boff][1];
              const float x2 = xv[m + aoff][boff][2];
              acc[m][dt][ht][0] += x0 * wvv[kh * 5 + 4];
              acc[m][dt][ht][0] += x1 * wvv[kh * 5 + 2];
              acc[m][dt][ht][0] += x2 * wvv[kh * 5 + 0];
              acc[m][dt][ht][1] += x1 * wvv[kh * 5 + 3];
              acc[m][dt][ht][1] += x2 * wvv[kh * 5 + 1];
            }
          }
        }
      }
    }
    __syncthreads();
  }
  if (t < 225) {
    float* pb = part + (size_t)n * Y_N;
#pragma unroll
    for (int m = 0; m < 3; ++m)
#pragma unroll
      for (int dt = 0; dt < 2; ++dt)
#pragma unroll
        for (int ht = 0; ht < 2; ++ht) {
          int od_g = 6 * dc + 2 * m + dt;
          int oh_g = 30 * hq + 2 * lmh + ht;
          int ow_g = 30 * wq + 2 * mw;
          *(float2*)&pb[(od_g * 60 + oh_g) * 60 + ow_g] =
              make_float2(acc[m][dt][ht][0], acc[m][dt][ht][1]);
        }
  }
}

__global__ __launch_bounds__(256) void pool_stage2(const float* __restrict__ part,
                                                   const float* __restrict__ ws,
                                                   float* __restrict__ out, int woff) {
  __shared__ __align__(16) float buf[2160];
  __shared__ float red[240];
  int blk = blockIdx.x;
  int hc = blk % 10, dc = (blk / 10) % 5, n = blk / 50;
  int t = threadIdx.x;
  const float* pb = part + (size_t)n * Y_N;
  for (int s = t; s < 540; s += 256) {
    int row = s / 15, c4 = s % 15;
    int od = row / 6, oh = row % 6;
    size_t idx = (size_t)((6 * dc + od) * 60 + (6 * hc + oh)) * 60 + 4 * c4;
    *(float4*)&buf[row * 60 + 4 * c4] = *(const float4*)&pb[idx];
  }
  __syncthreads();
  if (t < 240) {
    int wc = t / 24, sub = t % 24;
    float m = -3.4e38f;
#pragma unroll
    for (int k = 0; k < 9; ++k) {
      int e = sub + 24 * k;
      int od = e / 36, r = e % 36;
      int oh = r / 6, ow0 = r % 6;
      m = fmaxf(m, buf[(od * 6 + oh) * 60 + 6 * wc + ow0]);
    }
    red[t] = m;
  }
  __syncthreads();
  if (t < 10) {
    float mm = -3.4e38f;
#pragma unroll
    for (int s2 = 0; s2 < 24; ++s2) mm = fmaxf(mm, red[t * 24 + s2]);
    out[((n * 5 + dc) * 10 + hc) * 10 + t] = mm + ws[woff + 4096];
  }
}

// ---------------- launch ----------------------------------------------
extern "C" void kernel_launch(void* const* d_in, const int* in_sizes, int n_in,
                              void* d_out, int out_size, void* d_ws, size_t ws_size,
                              hipStream_t stream) {
  const float* x    = (const float*)d_in[0];
  const float* w    = (const float*)d_in[1];
  const float* bias = (const float*)d_in[2];
  float* outp = (float*)d_out;

  if (ws_size >= (size_t)NEED_FUSED) {
    ushort_t* xT = (ushort_t*)d_ws;
    ushort_t* Bt = (ushort_t*)((char*)d_ws + BT_BYTE_OFF);
    float* wsf   = (float*)((char*)d_ws + WSF_BYTE_OFF);
    unsigned* cnt = (unsigned*)((char*)d_ws + CNT_BYTE_OFF);
    hipMemsetAsync(cnt, 0, 128, stream);
    fused_all<<<400, 576, 0, stream>>>(x, w, bias, xT, Bt, wsf, cnt, outp);
    return;
  }

  // fp32 fallback (needs ~6.9 MB ws)
  float* ws = (float*)d_ws;
  const size_t need1 = ((size_t)1 * Y_TOT + 4097) * 4;
  if (ws_size >= need1) {
    int woff = Y_TOT;
    prep2<<<32, 128, 0, stream>>>(w, bias, ws, woff);
    conv_stage1<<<320, 256, 0, stream>>>(x, ws, ws, woff);
    pool_stage2<<<800, 256, 0, stream>>>(ws, ws, outp, woff);
  }
}

// Round 14
// 93.041 us; speedup vs baseline: 1.1998x; 1.1998x over previous
//
#include <hip/hip_runtime.h>

// y = convT3d(x, weight.sum(oc), stride=2, pad=2, k=5) + sum(bias); out = 6^3 stride-6 max.
// MFMA formulation (verified R6-R13, absmax 0.25): y[2m+t] = sum_{ic,abc} x[ic,m+1-abc]*w[ic,t+2abc]
// R14: ONE kernel, producer->consumer overlap, fixed R13 starvation: producer unit = FULL
//   (n,dpad) plane with ALL 576 threads, 272 units <= 400 blocks => ONE round. Blocks 272..298
//   build Btab (27 units). Release atomics cnt[n](17)/cnt[16](27); consumers spin+acquire then
//   run R11 conv core verbatim. All 400 blocks co-resident (3/CU) => deadlock-free.

typedef short v8s __attribute__((ext_vector_type(8)));
typedef float v4f __attribute__((ext_vector_type(4)));
typedef unsigned short ushort_t;

#define CHSTR 16384
#define NSTRIDE (32*CHSTR)
#define Y_N 108000
#define Y_TOT (16*Y_N)
#define XSTR 24

#define PLANE_US 36992u          // 34*34*32
#define ROW_US 1088u             // 34*32
#define XTN17 628864u            // per-n xT: 17 planes
#define BT_BYTE_OFF 20123648u    // xT = 16*17*PLANE_US*2
#define WSF_BYTE_OFF 20151296u   // +27*64*8*2
#define CNT_BYTE_OFF 20167684u   // +4097*4
#define NEED_FUSED (20167684u + 128u)

static __device__ __forceinline__ ushort_t f2bf(float f) {
  unsigned u = __builtin_bit_cast(unsigned, f);
  unsigned r = (u + 0x7FFFu + ((u >> 16) & 1u)) >> 16;
  return (ushort_t)r;
}

__global__ __launch_bounds__(576, 7) void fused_all(const float* __restrict__ x,
                                                    const float* __restrict__ wt,
                                                    const float* __restrict__ bias,
                                                    ushort_t* __restrict__ xT,
                                                    ushort_t* __restrict__ Btab,
                                                    float* __restrict__ wsf,
                                                    unsigned* __restrict__ cnt,
                                                    float* __restrict__ out) {
  __shared__ __align__(16) char smem[35328];
  int b = blockIdx.x, t = threadIdx.x;

  // ================= producer phase: one unit per block =================
  if (b < 272) {
    int tn = b / 17, dpad = b % 17;
    ushort_t* plane = xT + (size_t)(tn * 17 + dpad) * PLANE_US;
    int d = dpad - 1;
    if (d < 0) {
      // zero plane rows 0..31 (rows 32/33 never read)
      for (int j = 0; j < 8; ++j) {
        int s = t + 576 * j;
        if (s < 4352) {
          int row = s / 136, inner = s % 136;
          int wslot = inner >> 2, icq = inner & 3;
          *(uint4*)&plane[(size_t)row * ROW_US + wslot * 32 + icq * 8] = make_uint4(0, 0, 0, 0);
        }
      }
    } else {
      float* lb = (float*)smem;                 // [32 ic][8 h8][33 w] = 33792 B
      const float* xb = x + (size_t)tn * NSTRIDE + d * 1024;
      for (int cc = 0; cc < 4; ++cc) {
        // ---- stage: 2048 float4 loads (h = 8cc-1+h8)
        for (int j = 0; j < 4; ++j) {
          int s2 = t + 576 * j;
          if (s2 < 2048) {
            int wq = s2 & 7, h8 = (s2 >> 3) & 7, ic = s2 >> 6;
            int h = 8 * cc - 1 + h8;
            if (h >= 0) {
              float4 v = *(const float4*)&xb[(size_t)ic * CHSTR + h * 32 + wq * 4];
              float* L = lb + ic * 264 + h8 * 33 + wq * 4;
              L[0] = v.x; L[1] = v.y; L[2] = v.z; L[3] = v.w;
            }
          }
        }
        __syncthreads();
        // ---- emit: 1088 uint4 stores (rows 8cc..8cc+3+4)
        for (int j = 0; j < 2; ++j) {
          int s = t + 576 * j;
          if (s < 1088) {
            int icq = s & 3, q = s >> 2;
            int wslot = q % 34, r8 = q / 34;
            ushort_t o[8];
#pragma unroll
            for (int jj = 0; jj < 8; ++jj) o[jj] = 0;
            if (wslot >= 1 && wslot <= 32 && (8 * cc + r8) > 0) {
              int w2 = wslot - 1;
#pragma unroll
              for (int jj = 0; jj < 8; ++jj)
                o[jj] = f2bf(lb[(8 * icq + jj) * 264 + r8 * 33 + w2]);
            }
            uint4 pk;
            pk.x = (unsigned)o[0] | ((unsigned)o[1] << 16);
            pk.y = (unsigned)o[2] | ((unsigned)o[3] << 16);
            pk.z = (unsigned)o[4] | ((unsigned)o[5] << 16);
            pk.w = (unsigned)o[6] | ((unsigned)o[7] << 16);
            *(uint4*)&plane[(size_t)(8 * cc + r8) * ROW_US + wslot * 32 + icq * 8] = pk;
          }
        }
        __syncthreads();
      }
    }
    if (t == 0)
      __hip_atomic_fetch_add(&cnt[tn], 1u, __ATOMIC_RELEASE, __HIP_MEMORY_SCOPE_AGENT);
  } else if (b < 299) {
    // ---- prep unit: Btab from raw w (verified body), abc = b-272
    if (t < 256) {
      int abc = b - 272;
      int a = abc / 9, bb = (abc / 3) % 3, c = abc % 3;
      int half = t & 3;
      int l = t >> 2;
      int tt = l & 15, g = l >> 4;
      float v0 = 0.f, v1 = 0.f;
      if (tt < 8) {
        int td = tt & 1, th = (tt >> 1) & 1, tw = tt >> 2;
        int kd = td + 2 * a, kh = th + 2 * bb, kw = tw + 2 * c;
        if (kd < 5 && kh < 5 && kw < 5) {
          int off = kd * 25 + kh * 5 + kw;
          const float* wp0 = wt + (size_t)(8 * g + 2 * half) * 64 * 125 + off;
          const float* wp1 = wp0 + 64 * 125;
          float s0 = 0.f, s1 = 0.f;
#pragma unroll
          for (int oc = 0; oc < 64; ++oc) { s0 += wp0[oc * 125]; s1 += wp1[oc * 125]; }
          v0 = s0; v1 = s1;
        }
      }
      ((unsigned*)Btab)[(abc * 64 + l) * 4 + half] =
          (unsigned)f2bf(v0) | ((unsigned)f2bf(v1) << 16);
      if (abc == 0 && t == 0) {
        float bs = 0.f;
        for (int o = 0; o < 64; ++o) bs += bias[o];
        wsf[4096] = bs;
      }
    }
    __syncthreads();
    if (t == 0)
      __hip_atomic_fetch_add(&cnt[16], 1u, __ATOMIC_RELEASE, __HIP_MEMORY_SCOPE_AGENT);
  }

  // ================= consumer phase: wait for deps =================
  int OH2 = b % 5, OD = (b / 5) % 5, n = b / 25;
  if (t == 0) {
    while (__hip_atomic_load(&cnt[16], __ATOMIC_RELAXED, __HIP_MEMORY_SCOPE_AGENT) < 27u)
      __builtin_amdgcn_s_sleep(8);
    while (__hip_atomic_load(&cnt[n], __ATOMIC_RELAXED, __HIP_MEMORY_SCOPE_AGENT) < 17u)
      __builtin_amdgcn_s_sleep(8);
  }
  __syncthreads();
  __builtin_amdgcn_fence(__ATOMIC_ACQUIRE, "agent");

  // ================= conv core (R11 verbatim, LDS overlay) =================
  ushort_t* As0 = (ushort_t*)smem;
  ushort_t* As1 = (ushort_t*)(smem + 17408);
  float* ytile  = (float*)smem;
  float* red    = (float*)(smem + 34816);

  int wv = t >> 6, l = t & 63;
  int mdl = wv / 3, mhp = wv % 3;
  int tt = l & 15, g = l >> 4;

  const ushort_t* xn = xT + (size_t)n * XTN17;
  const ushort_t* slab0 = xn + ((size_t)(3 * OD) * 34 + 6 * OH2) * ROW_US;

  {
    uint4 v0 = *(const uint4*)(slab0 + (size_t)t * 8);
    uint4 v1;
    if (t < 512) v1 = *(const uint4*)(slab0 + (size_t)(t + 576) * 8);
    *(uint4*)&As0[t * 8] = v0;
    if (t < 512) *(uint4*)&As0[(t + 576) * 8] = v1;
  }
  __syncthreads();

  v4f acc[2][2];
#pragma unroll
  for (int m2 = 0; m2 < 2; ++m2)
#pragma unroll
    for (int wh = 0; wh < 2; ++wh) acc[m2][wh] = (v4f){0.f, 0.f, 0.f, 0.f};

  int lane_base = (2 * mhp) * ROW_US + tt * 32 + g * 8;

  for (int p = 0; p < 5; ++p) {
    uint4 v0, v1;
    if (p < 4) {
      const ushort_t* slab = slab0 + (size_t)(p + 1) * PLANE_US;
      v0 = *(const uint4*)(slab + (size_t)t * 8);
      if (t < 512) v1 = *(const uint4*)(slab + (size_t)(t + 576) * 8);
    }

    int a = mdl + 2 - p;
    if (0 <= a && a <= 2) {
      const ushort_t* Ab = (p & 1) ? As1 : As0;
      const ushort_t* Bg = Btab + ((size_t)(a * 9) * 64 + l) * 8;
#pragma unroll
      for (int c = 0; c < 3; ++c) {
        v8s bv0 = *(const v8s*)(Bg + (0 * 3 + c) * 512);
        v8s bv1 = *(const v8s*)(Bg + (1 * 3 + c) * 512);
        v8s bv2 = *(const v8s*)(Bg + (2 * 3 + c) * 512);
#pragma unroll
        for (int wh = 0; wh < 2; ++wh) {
          const ushort_t* ap = Ab + lane_base + (2 - c + 16 * wh) * 32;
          v8s a0 = *(const v8s*)(ap);
          v8s a1 = *(const v8s*)(ap + 1 * ROW_US);
          v8s a2 = *(const v8s*)(ap + 2 * ROW_US);
          v8s a3 = *(const v8s*)(ap + 3 * ROW_US);
          acc[0][wh] = __builtin_amdgcn_mfma_f32_16x16x32_bf16(a0, bv2, acc[0][wh], 0, 0, 0);
          acc[0][wh] = __builtin_amdgcn_mfma_f32_16x16x32_bf16(a1, bv1, acc[0][wh], 0, 0, 0);
          acc[0][wh] = __builtin_amdgcn_mfma_f32_16x16x32_bf16(a2, bv0, acc[0][wh], 0, 0, 0);
          acc[1][wh] = __builtin_amdgcn_mfma_f32_16x16x32_bf16(a1, bv2, acc[1][wh], 0, 0, 0);
          acc[1][wh] = __builtin_amdgcn_mfma_f32_16x16x32_bf16(a2, bv1, acc[1][wh], 0, 0, 0);
          acc[1][wh] = __builtin_amdgcn_mfma_f32_16x16x32_bf16(a3, bv0, acc[1][wh], 0, 0, 0);
        }
      }
    }

    if (p < 4) {
      ushort_t* dst = (p & 1) ? As0 : As1;
      *(uint4*)&dst[t * 8] = v0;
      if (t < 512) *(uint4*)&dst[(t + 576) * 8] = v1;
      __syncthreads();
    }
  }

  __syncthreads();
  if (tt < 8) {
    int td = tt & 1, th = (tt >> 1) & 1, tw = tt >> 2;
    int odl = 2 * mdl + td;
#pragma unroll
    for (int m2 = 0; m2 < 2; ++m2) {
      int ohl = 2 * (2 * mhp + m2) + th;
      float* yrow = &ytile[(odl * 12 + ohl) * 64];
#pragma unroll
      for (int wh = 0; wh < 2; ++wh)
#pragma unroll
        for (int i = 0; i < 4; ++i)
          yrow[2 * (16 * wh + 4 * g + i) + tw] = acc[m2][wh][i];
    }
  }
  __syncthreads();

  if (t < 120) {
    int OW = t % 10, p_oh = (t / 10) & 1, odl = t / 20;
    float m = -3.4e38f;
    for (int oh = 0; oh < 6; ++oh)
#pragma unroll
      for (int j = 0; j < 6; ++j)
        m = fmaxf(m, ytile[(odl * 12 + 6 * p_oh + oh) * 64 + 6 * OW + j]);
    red[t] = m;
  }
  __syncthreads();
  if (t < 20) {
    int OW = t % 10, p_oh = t / 10;
    float m = red[p_oh * 10 + OW];
#pragma unroll
    for (int odl = 1; odl < 6; ++odl) m = fmaxf(m, red[odl * 20 + p_oh * 10 + OW]);
    out[((n * 5 + OD) * 10 + (2 * OH2 + p_oh)) * 10 + OW] = m + wsf[4096];
  }
}

// ================= fallback: R5 verified fp32 path (tiny ws) ===========
__global__ __launch_bounds__(128) void prep2(const float* __restrict__ w,
                                             const float* __restrict__ bias,
                                             float* __restrict__ ws, int woff) {
  int i = blockIdx.x, t = threadIdx.x;
  if (t < 125) {
    const float* wp = w + (size_t)i * 64 * 125 + t;
    float v = 0.f;
#pragma unroll
    for (int o = 0; o < 64; ++o) v += wp[o * 125];
    ws[woff + i * 128 + t] = v;
  }
  if (i == 0 && t == 126) {
    float b = 0.f;
    for (int o = 0; o < 64; ++o) b += bias[o];
    ws[woff + 4096] = b;
  }
}

__global__ __launch_bounds__(256, 4) void conv_stage1(const float* __restrict__ x,
                                                      const float* __restrict__ ws,
                                                      float* part, int woff) {
  __shared__ __align__(16) float xs[170 * XSTR];
  int blk = blockIdx.x;
  int s0 = blk % 320;
  int wq = s0 & 1, hq = (s0 >> 1) & 1, dc = (s0 >> 2) % 5, n = s0 / 20;
  int t = threadIdx.x;
  int mw = t % 15, lmh = t / 15;
  int id_base = 3 * dc - 1, ih_base = 15 * hq - 1;
  int iwb = wq ? 12 : -4;
  int cb = mw + (wq ? 2 : 3);
  const float* xn = x + (size_t)n * NSTRIDE;
  const float* wsw = ws + woff;
  float acc[3][2][2][2] = {{{{0.f}}}};
  for (int phs = 0; phs < 16; ++phs) {
    for (int s = t; s < 1700; s += 256) {
      int c2 = s % 10, row = s / 10;
      int bh = row % 17, q = row / 17;
      int ad = q % 5, lic = q / 5;
      int id = id_base + ad, ih = ih_base + bh, iw = iwb + 2 * c2;
      float2 v = make_float2(0.f, 0.f);
      if ((id | ih | iw) >= 0)
        v = *(const float2*)&xn[(size_t)(phs * 2 + lic) * CHSTR + (id * 32 + ih) * 32 + iw];
      *(float2*)&xs[row * XSTR + 2 * c2] = v;
    }
    __syncthreads();
    if (t < 225) {
#pragma unroll
      for (int lic = 0; lic < 2; ++lic) {
        const float* wc = wsw + (size_t)(phs * 2 + lic) * 128;
        const float* xc = &xs[(lic * 85 + lmh) * XSTR + cb];
        float xv[5][3][3];
#pragma unroll
        for (int a = 0; a < 5; ++a)
#pragma unroll
          for (int b = 0; b < 3; ++b) {
            const float* xr = xc + (a * 17 + b) * XSTR;
            xv[a][b][0] = xr[0]; xv[a][b][1] = xr[1]; xv[a][b][2] = xr[2];
          }
#pragma unroll
        for (int kd = 0; kd < 5; ++kd) {
          constexpr int DT[5] = {0, 1, 0, 1, 0};
          constexpr int AOFF[5] = {2, 2, 1, 1, 0};
          const int dt = DT[kd], aoff = AOFF[kd];
          float wvv[25];
#pragma unroll
          for (int j = 0; j < 25; ++j) wvv[j] = wc[kd * 25 + j];
#pragma unroll
          for (int kh = 0; kh < 5; ++kh) {
            constexpr int HT[5] = {0, 1, 0, 1, 0};
            constexpr int BOFF[5] = {2, 2, 1, 1, 0};
            const int ht = HT[kh], boff = BOFF[kh];
#pragma unroll
            for (int m = 0; m < 3; ++m) {
              const float x0 = xv[m + aoff][boff][0];
              const float x1 = xv[m + aoff][boff][1];
              const float x2 = xv[m + aoff][boff][2];
              acc[m][dt][ht][0] += x0 * wvv[kh * 5 + 4];
              acc[m][dt][ht][0] += x1 * wvv[kh * 5 + 2];
              acc[m][dt][ht][0] += x2 * wvv[kh * 5 + 0];
              acc[m][dt][ht][1] += x1 * wvv[kh * 5 + 3];
              acc[m][dt][ht][1] += x2 * wvv[kh * 5 + 1];
            }
          }
        }
      }
    }
    __syncthreads();
  }
  if (t < 225) {
    float* pb = part + (size_t)n * Y_N;
#pragma unroll
    for (int m = 0; m < 3; ++m)
#pragma unroll
      for (int dt = 0; dt < 2; ++dt)
#pragma unroll
        for (int ht = 0; ht < 2; ++ht) {
          int od_g = 6 * dc + 2 * m + dt;
          int oh_g = 30 * hq + 2 * lmh + ht;
          int ow_g = 30 * wq + 2 * mw;
          *(float2*)&pb[(od_g * 60 + oh_g) * 60 + ow_g] =
              make_float2(acc[m][dt][ht][0], acc[m][dt][ht][1]);
        }
  }
}

__global__ __launch_bounds__(256) void pool_stage2(const float* __restrict__ part,
                                                   const float* __restrict__ ws,
                                                   float* __restrict__ out, int woff) {
  __shared__ __align__(16) float buf[2160];
  __shared__ float red[240];
  int blk = blockIdx.x;
  int hc = blk % 10, dc = (blk / 10) % 5, n = blk / 50;
  int t = threadIdx.x;
  const float* pb = part + (size_t)n * Y_N;
  for (int s = t; s < 540; s += 256) {
    int row = s / 15, c4 = s % 15;
    int od = row / 6, oh = row % 6;
    size_t idx = (size_t)((6 * dc + od) * 60 + (6 * hc + oh)) * 60 + 4 * c4;
    *(float4*)&buf[row * 60 + 4 * c4] = *(const float4*)&pb[idx];
  }
  __syncthreads();
  if (t < 240) {
    int wc = t / 24, sub = t % 24;
    float m = -3.4e38f;
#pragma unroll
    for (int k = 0; k < 9; ++k) {
      int e = sub + 24 * k;
      int od = e / 36, r = e % 36;
      int oh = r / 6, ow0 = r % 6;
      m = fmaxf(m, buf[(od * 6 + oh) * 60 + 6 * wc + ow0]);
    }
    red[t] = m;
  }
  __syncthreads();
  if (t < 10) {
    float mm = -3.4e38f;
#pragma unroll
    for (int s2 = 0; s2 < 24; ++s2) mm = fmaxf(mm, red[t * 24 + s2]);
    out[((n * 5 + dc) * 10 + hc) * 10 + t] = mm + ws[woff + 4096];
  }
}

// ---------------- launch ----------------------------------------------
extern "C" void kernel_launch(void* const* d_in, const int* in_sizes, int n_in,
                              void* d_out, int out_size, void* d_ws, size_t ws_size,
                              hipStream_t stream) {
  const float* x    = (const float*)d_in[0];
  const float* w    = (const float*)d_in[1];
  const float* bias = (const float*)d_in[2];
  float* outp = (float*)d_out;

  if (ws_size >= (size_t)NEED_FUSED) {
    ushort_t* xT = (ushort_t*)d_ws;
    ushort_t* Bt = (ushort_t*)((char*)d_ws + BT_BYTE_OFF);
    float* wsf   = (float*)((char*)d_ws + WSF_BYTE_OFF);
    unsigned* cnt = (unsigned*)((char*)d_ws + CNT_BYTE_OFF);
    hipMemsetAsync(cnt, 0, 128, stream);
    fused_all<<<400, 576, 0, stream>>>(x, w, bias, xT, Bt, wsf, cnt, outp);
    return;
  }

  // fp32 fallback (needs ~6.9 MB ws)
  float* ws = (float*)d_ws;
  const size_t need1 = ((size_t)1 * Y_TOT + 4097) * 4;
  if (ws_size >= need1) {
    int woff = Y_TOT;
    prep2<<<32, 128, 0, stream>>>(w, bias, ws, woff);
    conv_stage1<<<320, 256, 0, stream>>>(x, ws, ws, woff);
    pool_stage2<<<800, 256, 0, stream>>>(ws, ws, outp, woff);
  }
}

// Round 15
// 35.353 us; speedup vs baseline: 3.1575x; 2.6317x over previous
//
#include <hip/hip_runtime.h>

// y = convT3d(x, weight.sum(oc), stride=2, pad=2, k=5) + sum(bias); out = 6^3 stride-6 max.
// MFMA formulation (verified R6-R14, absmax 0.25): y[2m+t] = sum_{ic,abc} x[ic,m+1-abc]*w[ic,t+2abc]
//   D[16 w-cells x 8 parities] += A[cells x 32ic] * B[32ic x parities], 27 (a,b,c) chunks.
// xT: bf16 [n][q=dpad-1: 16 planes][hpad 34][wpad 34][ic 32]; dpad=0 (all-zero) NOT stored --
//   conv zero-fills LDS for the one case that reads it (OD=0 prologue).
// R15: transpose = R14's producer body standalone (full plane/block, 576 thr, 4 chunk-phases,
//   256+27 blocks); conv = R11 core verbatim (2-mh-row waves, contiguous slab dbuf staging,
//   global Btab B-frags). Two kernels, stream-ordered. (R13/R14 single-kernel overlap: 2x
//   refuted; R10/R12 direct fp32 staging: 2x refuted.)

typedef short v8s __attribute__((ext_vector_type(8)));
typedef float v4f __attribute__((ext_vector_type(4)));
typedef unsigned short ushort_t;

#define CHSTR 16384
#define NSTRIDE (32*CHSTR)
#define Y_N 108000
#define Y_TOT (16*Y_N)
#define XSTR 24

#define PLANE_US 36992u          // 34*34*32
#define ROW_US 1088u             // 34*32
#define XTN16 591872u            // per-n xT: 16 planes
#define BT_BYTE_OFF 18939904u    // xT = 16*XTN16*2
#define WSF_BYTE_OFF 18967552u   // +27*64*8*2
#define NEED_MFMA (18967552u + 4097u*4u)

static __device__ __forceinline__ ushort_t f2bf(float f) {
  unsigned u = __builtin_bit_cast(unsigned, f);
  unsigned r = (u + 0x7FFFu + ((u >> 16) & 1u)) >> 16;
  return (ushort_t)r;
}

// ---------------- transpose x -> xT bf16 (full plane/block) + prep ------
// blocks 0..255: (tn, q) plane; blocks 256..282: Btab prep unit abc=b-256.
__global__ __launch_bounds__(576) void transpose_x(const float* __restrict__ x,
                                                   const float* __restrict__ wt,
                                                   const float* __restrict__ bias,
                                                   ushort_t* __restrict__ xT,
                                                   ushort_t* __restrict__ Btab,
                                                   float* __restrict__ wsf) {
  __shared__ __align__(16) float lb[32 * 264];   // [32 ic][8 h8][33 w] = 33792 B
  int b = blockIdx.x, t = threadIdx.x;

  if (b >= 256) {                 // ---- prep path (verified R10/R12 body)
    if (t < 256) {
      int abc = b - 256;
      int a = abc / 9, bb = (abc / 3) % 3, c = abc % 3;
      int half = t & 3;
      int l = t >> 2;
      int tt = l & 15, g = l >> 4;
      float v0 = 0.f, v1 = 0.f;
      if (tt < 8) {
        int td = tt & 1, th = (tt >> 1) & 1, tw = tt >> 2;
        int kd = td + 2 * a, kh = th + 2 * bb, kw = tw + 2 * c;
        if (kd < 5 && kh < 5 && kw < 5) {
          int off = kd * 25 + kh * 5 + kw;
          const float* wp0 = wt + (size_t)(8 * g + 2 * half) * 64 * 125 + off;
          const float* wp1 = wp0 + 64 * 125;
          float s0 = 0.f, s1 = 0.f;
#pragma unroll
          for (int oc = 0; oc < 64; ++oc) { s0 += wp0[oc * 125]; s1 += wp1[oc * 125]; }
          v0 = s0; v1 = s1;
        }
      }
      ((unsigned*)Btab)[(abc * 64 + l) * 4 + half] =
          (unsigned)f2bf(v0) | ((unsigned)f2bf(v1) << 16);
      if (abc == 0 && t == 0) {
        float bs = 0.f;
        for (int o = 0; o < 64; ++o) bs += bias[o];
        wsf[4096] = bs;
      }
    }
    return;
  }

  int tn = b >> 4, q = b & 15;    // plane q <-> dpad q+1, real d = q
  ushort_t* plane = xT + (size_t)(tn * 16 + q) * PLANE_US;
  const float* xb = x + (size_t)tn * NSTRIDE + q * 1024;

  for (int cc = 0; cc < 4; ++cc) {
    // ---- stage fp32: rows h = 8cc-1+h8 (h=-1 only cc=0,h8=0)
    for (int j = 0; j < 4; ++j) {
      int s2 = t + 576 * j;
      if (s2 < 2048) {
        int wq = s2 & 7, h8 = (s2 >> 3) & 7, ic = s2 >> 6;
        int h = 8 * cc - 1 + h8;
        if (h >= 0) {
          float4 v = *(const float4*)&xb[(size_t)ic * CHSTR + h * 32 + wq * 4];
          float* L = lb + ic * 264 + h8 * 33 + wq * 4;
          L[0] = v.x; L[1] = v.y; L[2] = v.z; L[3] = v.w;
        }
      }
    }
    __syncthreads();
    // ---- emit bf16 rows 8cc..8cc+7 (row 0 = h=-1 -> zeros; wslot 0,33 -> zeros)
    for (int j = 0; j < 2; ++j) {
      int s = t + 576 * j;
      if (s < 1088) {
        int icq = s & 3, qq = s >> 2;
        int wslot = qq % 34, r8 = qq / 34;
        int row = 8 * cc + r8;
        ushort_t o[8];
#pragma unroll
        for (int jj = 0; jj < 8; ++jj) o[jj] = 0;
        if (wslot >= 1 && wslot <= 32 && row > 0) {
          int w2 = wslot - 1;
#pragma unroll
          for (int jj = 0; jj < 8; ++jj)
            o[jj] = f2bf(lb[(8 * icq + jj) * 264 + r8 * 33 + w2]);
        }
        uint4 pk;
        pk.x = (unsigned)o[0] | ((unsigned)o[1] << 16);
        pk.y = (unsigned)o[2] | ((unsigned)o[3] << 16);
        pk.z = (unsigned)o[4] | ((unsigned)o[5] << 16);
        pk.w = (unsigned)o[6] | ((unsigned)o[7] << 16);
        *(uint4*)&plane[(size_t)row * ROW_US + wslot * 32 + icq * 8] = pk;
      }
    }
    __syncthreads();
  }
}

// ---------------- fused MFMA conv + 6^3 pool (R11 core) -----------------
// 400 blocks = (n, OD, OH2); 576 threads = 9 waves (mdl, mh-pair).
__global__ __launch_bounds__(576, 7) void conv_mfma6(const ushort_t* __restrict__ xT,
                                                     const ushort_t* __restrict__ Btab,
                                                     const float* __restrict__ wsf,
                                                     float* __restrict__ out) {
  __shared__ __align__(16) char smem[35328];
  ushort_t* As0 = (ushort_t*)smem;                 // 17408 B (8r x 34c x 32ic)
  ushort_t* As1 = (ushort_t*)(smem + 17408);       // 17408 B
  float* ytile  = (float*)smem;                    // overlays dead A-bufs
  float* red    = (float*)(smem + 34816);          // 480 B

  int blk = blockIdx.x;
  int OH2 = blk % 5, OD = (blk / 5) % 5, n = blk / 25;
  int t = threadIdx.x;
  int wv = t >> 6, l = t & 63;
  int mdl = wv / 3, mhp = wv % 3;
  int tt = l & 15, g = l >> 4;

  const ushort_t* xn = xT + (size_t)n * XTN16;
  // phase p slab: plane q = 3OD+p-1, rows 6OH2..6OH2+7 (contiguous 8704 ushorts)
  int rowoff = 6 * OH2 * (int)ROW_US;

  // ---- prologue: plane q = 3OD-1 (q=-1 iff OD==0 -> zero-fill)
  if (OD == 0) {
    for (int j = 0; j < 2; ++j) {
      int s = t + 576 * j;
      if (s < 1088) *(uint4*)&As0[s * 8] = make_uint4(0, 0, 0, 0);
    }
  } else {
    const ushort_t* slab = xn + (size_t)(3 * OD - 1) * PLANE_US + rowoff;
    uint4 v0 = *(const uint4*)(slab + (size_t)t * 8);
    uint4 v1;
    if (t < 512) v1 = *(const uint4*)(slab + (size_t)(t + 576) * 8);
    *(uint4*)&As0[t * 8] = v0;
    if (t < 512) *(uint4*)&As0[(t + 576) * 8] = v1;
  }
  __syncthreads();

  v4f acc[2][2];
#pragma unroll
  for (int m2 = 0; m2 < 2; ++m2)
#pragma unroll
    for (int wh = 0; wh < 2; ++wh) acc[m2][wh] = (v4f){0.f, 0.f, 0.f, 0.f};

  int lane_base = (2 * mhp) * ROW_US + tt * 32 + g * 8;

  for (int p = 0; p < 5; ++p) {
    // ---- T14: issue next plane's loads early (plane q = 3OD+p >= 0 always)
    uint4 v0, v1;
    if (p < 4) {
      const ushort_t* slab = xn + (size_t)(3 * OD + p) * PLANE_US + rowoff;
      v0 = *(const uint4*)(slab + (size_t)t * 8);
      if (t < 512) v1 = *(const uint4*)(slab + (size_t)(t + 576) * 8);
    }

    // ---- compute phase p (wave active if a = mdl+2-p in [0,2])
    int a = mdl + 2 - p;
    if (0 <= a && a <= 2) {
      const ushort_t* Ab = (p & 1) ? As1 : As0;
      const ushort_t* Bg = Btab + ((size_t)(a * 9) * 64 + l) * 8;
#pragma unroll
      for (int c = 0; c < 3; ++c) {
        v8s bv0 = *(const v8s*)(Bg + (0 * 3 + c) * 512);
        v8s bv1 = *(const v8s*)(Bg + (1 * 3 + c) * 512);
        v8s bv2 = *(const v8s*)(Bg + (2 * 3 + c) * 512);
#pragma unroll
        for (int wh = 0; wh < 2; ++wh) {
          const ushort_t* ap = Ab + lane_base + (2 - c + 16 * wh) * 32;
          v8s a0 = *(const v8s*)(ap);
          v8s a1 = *(const v8s*)(ap + 1 * ROW_US);
          v8s a2 = *(const v8s*)(ap + 2 * ROW_US);
          v8s a3 = *(const v8s*)(ap + 3 * ROW_US);
          // row j feeds (m2=0, b=2-j) and (m2=1, b=3-j)
          acc[0][wh] = __builtin_amdgcn_mfma_f32_16x16x32_bf16(a0, bv2, acc[0][wh], 0, 0, 0);
          acc[0][wh] = __builtin_amdgcn_mfma_f32_16x16x32_bf16(a1, bv1, acc[0][wh], 0, 0, 0);
          acc[0][wh] = __builtin_amdgcn_mfma_f32_16x16x32_bf16(a2, bv0, acc[0][wh], 0, 0, 0);
          acc[1][wh] = __builtin_amdgcn_mfma_f32_16x16x32_bf16(a1, bv2, acc[1][wh], 0, 0, 0);
          acc[1][wh] = __builtin_amdgcn_mfma_f32_16x16x32_bf16(a2, bv1, acc[1][wh], 0, 0, 0);
          acc[1][wh] = __builtin_amdgcn_mfma_f32_16x16x32_bf16(a3, bv0, acc[1][wh], 0, 0, 0);
        }
      }
    }

    // ---- write next plane into other buffer, one barrier
    if (p < 4) {
      ushort_t* dst = (p & 1) ? As0 : As1;
      *(uint4*)&dst[t * 8] = v0;
      if (t < 512) *(uint4*)&dst[(t + 576) * 8] = v1;
      __syncthreads();
    }
  }

  // ---- D scatter to ytile (C/D layout verified R6)
  __syncthreads();
  if (tt < 8) {
    int td = tt & 1, th = (tt >> 1) & 1, tw = tt >> 2;
    int odl = 2 * mdl + td;
#pragma unroll
    for (int m2 = 0; m2 < 2; ++m2) {
      int ohl = 2 * (2 * mhp + m2) + th;
      float* yrow = &ytile[(odl * 12 + ohl) * 64];
#pragma unroll
      for (int wh = 0; wh < 2; ++wh)
#pragma unroll
        for (int i = 0; i < 4; ++i)
          yrow[2 * (16 * wh + 4 * g + i) + tw] = acc[m2][wh][i];
    }
  }
  __syncthreads();

  // ---- 6^3 pool: 120 threads = (odl 6, p_oh 2, OW 10)
  if (t < 120) {
    int OW = t % 10, p_oh = (t / 10) & 1, odl = t / 20;
    float m = -3.4e38f;
    for (int oh = 0; oh < 6; ++oh)
#pragma unroll
      for (int j = 0; j < 6; ++j)
        m = fmaxf(m, ytile[(odl * 12 + 6 * p_oh + oh) * 64 + 6 * OW + j]);
    red[t] = m;
  }
  __syncthreads();
  if (t < 20) {
    int OW = t % 10, p_oh = t / 10;
    float m = red[p_oh * 10 + OW];
#pragma unroll
    for (int odl = 1; odl < 6; ++odl) m = fmaxf(m, red[odl * 20 + p_oh * 10 + OW]);
    out[((n * 5 + OD) * 10 + (2 * OH2 + p_oh)) * 10 + OW] = m + wsf[4096];
  }
}

// ================= fallback: R5 verified fp32 path (tiny ws) ===========
__global__ __launch_bounds__(128) void prep2(const float* __restrict__ w,
                                             const float* __restrict__ bias,
                                             float* __restrict__ ws, int woff) {
  int i = blockIdx.x, t = threadIdx.x;
  if (t < 125) {
    const float* wp = w + (size_t)i * 64 * 125 + t;
    float v = 0.f;
#pragma unroll
    for (int o = 0; o < 64; ++o) v += wp[o * 125];
    ws[woff + i * 128 + t] = v;
  }
  if (i == 0 && t == 126) {
    float b = 0.f;
    for (int o = 0; o < 64; ++o) b += bias[o];
    ws[woff + 4096] = b;
  }
}

__global__ __launch_bounds__(256, 4) void conv_stage1(const float* __restrict__ x,
                                                      const float* __restrict__ ws,
                                                      float* part, int woff) {
  __shared__ __align__(16) float xs[170 * XSTR];
  int blk = blockIdx.x;
  int s0 = blk % 320;
  int wq = s0 & 1, hq = (s0 >> 1) & 1, dc = (s0 >> 2) % 5, n = s0 / 20;
  int t = threadIdx.x;
  int mw = t % 15, lmh = t / 15;
  int id_base = 3 * dc - 1, ih_base = 15 * hq - 1;
  int iwb = wq ? 12 : -4;
  int cb = mw + (wq ? 2 : 3);
  const float* xn = x + (size_t)n * NSTRIDE;
  const float* wsw = ws + woff;
  float acc[3][2][2][2] = {{{{0.f}}}};
  for (int phs = 0; phs < 16; ++phs) {
    for (int s = t; s < 1700; s += 256) {
      int c2 = s % 10, row = s / 10;
      int bh = row % 17, q = row / 17;
      int ad = q % 5, lic = q / 5;
      int id = id_base + ad, ih = ih_base + bh, iw = iwb + 2 * c2;
      float2 v = make_float2(0.f, 0.f);
      if ((id | ih | iw) >= 0)
        v = *(const float2*)&xn[(size_t)(phs * 2 + lic) * CHSTR + (id * 32 + ih) * 32 + iw];
      *(float2*)&xs[row * XSTR + 2 * c2] = v;
    }
    __syncthreads();
    if (t < 225) {
#pragma unroll
      for (int lic = 0; lic < 2; ++lic) {
        const float* wc = wsw + (size_t)(phs * 2 + lic) * 128;
        const float* xc = &xs[(lic * 85 + lmh) * XSTR + cb];
        float xv[5][3][3];
#pragma unroll
        for (int a = 0; a < 5; ++a)
#pragma unroll
          for (int b = 0; b < 3; ++b) {
            const float* xr = xc + (a * 17 + b) * XSTR;
            xv[a][b][0] = xr[0]; xv[a][b][1] = xr[1]; xv[a][b][2] = xr[2];
          }
#pragma unroll
        for (int kd = 0; kd < 5; ++kd) {
          constexpr int DT[5] = {0, 1, 0, 1, 0};
          constexpr int AOFF[5] = {2, 2, 1, 1, 0};
          const int dt = DT[kd], aoff = AOFF[kd];
          float wvv[25];
#pragma unroll
          for (int j = 0; j < 25; ++j) wvv[j] = wc[kd * 25 + j];
#pragma unroll
          for (int kh = 0; kh < 5; ++kh) {
            constexpr int HT[5] = {0, 1, 0, 1, 0};
            constexpr int BOFF[5] = {2, 2, 1, 1, 0};
            const int ht = HT[kh], boff = BOFF[kh];
#pragma unroll
            for (int m = 0; m < 3; ++m) {
              const float x0 = xv[m + aoff][boff][0];
              const float x1 = xv[m + aoff][boff][1];
              const float x2 = xv[m + aoff][boff][2];
              acc[m][dt][ht][0] += x0 * wvv[kh * 5 + 4];
              acc[m][dt][ht][0] += x1 * wvv[kh * 5 + 2];
              acc[m][dt][ht][0] += x2 * wvv[kh * 5 + 0];
              acc[m][dt][ht][1] += x1 * wvv[kh * 5 + 3];
              acc[m][dt][ht][1] += x2 * wvv[kh * 5 + 1];
            }
          }
        }
      }
    }
    __syncthreads();
  }
  if (t < 225) {
    float* pb = part + (size_t)n * Y_N;
#pragma unroll
    for (int m = 0; m < 3; ++m)
#pragma unroll
      for (int dt = 0; dt < 2; ++dt)
#pragma unroll
        for (int ht = 0; ht < 2; ++ht) {
          int od_g = 6 * dc + 2 * m + dt;
          int oh_g = 30 * hq + 2 * lmh + ht;
          int ow_g = 30 * wq + 2 * mw;
          *(float2*)&pb[(od_g * 60 + oh_g) * 60 + ow_g] =
              make_float2(acc[m][dt][ht][0], acc[m][dt][ht][1]);
        }
  }
}

__global__ __launch_bounds__(256) void pool_stage2(const float* __restrict__ part,
                                                   const float* __restrict__ ws,
                                                   float* __restrict__ out, int woff) {
  __shared__ __align__(16) float buf[2160];
  __shared__ float red[240];
  int blk = blockIdx.x;
  int hc = blk % 10, dc = (blk / 10) % 5, n = blk / 50;
  int t = threadIdx.x;
  const float* pb = part + (size_t)n * Y_N;
  for (int s = t; s < 540; s += 256) {
    int row = s / 15, c4 = s % 15;
    int od = row / 6, oh = row % 6;
    size_t idx = (size_t)((6 * dc + od) * 60 + (6 * hc + oh)) * 60 + 4 * c4;
    *(float4*)&buf[row * 60 + 4 * c4] = *(const float4*)&pb[idx];
  }
  __syncthreads();
  if (t < 240) {
    int wc = t / 24, sub = t % 24;
    float m = -3.4e38f;
#pragma unroll
    for (int k = 0; k < 9; ++k) {
      int e = sub + 24 * k;
      int od = e / 36, r = e % 36;
      int oh = r / 6, ow0 = r % 6;
      m = fmaxf(m, buf[(od * 6 + oh) * 60 + 6 * wc + ow0]);
    }
    red[t] = m;
  }
  __syncthreads();
  if (t < 10) {
    float mm = -3.4e38f;
#pragma unroll
    for (int s2 = 0; s2 < 24; ++s2) mm = fmaxf(mm, red[t * 24 + s2]);
    out[((n * 5 + dc) * 10 + hc) * 10 + t] = mm + ws[woff + 4096];
  }
}

// ---------------- launch ----------------------------------------------
extern "C" void kernel_launch(void* const* d_in, const int* in_sizes, int n_in,
                              void* d_out, int out_size, void* d_ws, size_t ws_size,
                              hipStream_t stream) {
  const float* x    = (const float*)d_in[0];
  const float* w    = (const float*)d_in[1];
  const float* bias = (const float*)d_in[2];
  float* outp = (float*)d_out;

  if (ws_size >= (size_t)NEED_MFMA) {
    ushort_t* xT = (ushort_t*)d_ws;
    ushort_t* Bt = (ushort_t*)((char*)d_ws + BT_BYTE_OFF);
    float* wsf   = (float*)((char*)d_ws + WSF_BYTE_OFF);
    transpose_x<<<256 + 27, 576, 0, stream>>>(x, w, bias, xT, Bt, wsf);
    conv_mfma6<<<400, 576, 0, stream>>>(xT, Bt, wsf, outp);
    return;
  }

  // fp32 fallback (needs ~6.9 MB ws)
  float* ws = (float*)d_ws;
  const size_t need1 = ((size_t)1 * Y_TOT + 4097) * 4;
  if (ws_size >= need1) {
    int woff = Y_TOT;
    prep2<<<32, 128, 0, stream>>>(w, bias, ws, woff);
    conv_stage1<<<320, 256, 0, stream>>>(x, ws, ws, woff);
    pool_stage2<<<800, 256, 0, stream>>>(ws, ws, outp, woff);
  }
}

// Round 16
// 32.625 us; speedup vs baseline: 3.4216x; 1.0836x over previous
//
#include <hip/hip_runtime.h>

// y = convT3d(x, weight.sum(oc), stride=2, pad=2, k=5) + sum(bias); out = 6^3 stride-6 max.
// MFMA formulation (verified R6-R15, absmax 0.25): y[2m+t] = sum_{ic,abc} x[ic,m+1-abc]*w[ic,t+2abc]
//   D[16 w-cells x 8 parities] += A[cells x 32ic] * B[32ic x parities], 27 (a,b,c) chunks.
// xT: bf16 [n][q=dpad-1: 16 planes][hpad 34][wpad 34][ic 32]; dpad=0 (zero) not stored.
// R16: R15 + (1) conv n->XCD affinity swizzle (blk&7 = xcd owns images 2*xcd, 2*xcd+1 so the
//   1.84x xT re-read redundancy lands in that XCD's 4MB L2), (2) s_setprio(1) around the MFMA
//   cluster (T5: conv phases have load-issuing vs MFMA wave role-split).

typedef short v8s __attribute__((ext_vector_type(8)));
typedef float v4f __attribute__((ext_vector_type(4)));
typedef unsigned short ushort_t;

#define CHSTR 16384
#define NSTRIDE (32*CHSTR)
#define Y_N 108000
#define Y_TOT (16*Y_N)
#define XSTR 24

#define PLANE_US 36992u          // 34*34*32
#define ROW_US 1088u             // 34*32
#define XTN16 591872u            // per-n xT: 16 planes
#define BT_BYTE_OFF 18939904u    // xT = 16*XTN16*2
#define WSF_BYTE_OFF 18967552u   // +27*64*8*2
#define NEED_MFMA (18967552u + 4097u*4u)

static __device__ __forceinline__ ushort_t f2bf(float f) {
  unsigned u = __builtin_bit_cast(unsigned, f);
  unsigned r = (u + 0x7FFFu + ((u >> 16) & 1u)) >> 16;
  return (ushort_t)r;
}

// ---------------- transpose x -> xT bf16 (full plane/block) + prep ------
// blocks 0..255: (tn, q) plane; blocks 256..282: Btab prep unit abc=b-256. (R15 verbatim)
__global__ __launch_bounds__(576) void transpose_x(const float* __restrict__ x,
                                                   const float* __restrict__ wt,
                                                   const float* __restrict__ bias,
                                                   ushort_t* __restrict__ xT,
                                                   ushort_t* __restrict__ Btab,
                                                   float* __restrict__ wsf) {
  __shared__ __align__(16) float lb[32 * 264];   // [32 ic][8 h8][33 w] = 33792 B
  int b = blockIdx.x, t = threadIdx.x;

  if (b >= 256) {                 // ---- prep path (verified R10/R12 body)
    if (t < 256) {
      int abc = b - 256;
      int a = abc / 9, bb = (abc / 3) % 3, c = abc % 3;
      int half = t & 3;
      int l = t >> 2;
      int tt = l & 15, g = l >> 4;
      float v0 = 0.f, v1 = 0.f;
      if (tt < 8) {
        int td = tt & 1, th = (tt >> 1) & 1, tw = tt >> 2;
        int kd = td + 2 * a, kh = th + 2 * bb, kw = tw + 2 * c;
        if (kd < 5 && kh < 5 && kw < 5) {
          int off = kd * 25 + kh * 5 + kw;
          const float* wp0 = wt + (size_t)(8 * g + 2 * half) * 64 * 125 + off;
          const float* wp1 = wp0 + 64 * 125;
          float s0 = 0.f, s1 = 0.f;
#pragma unroll
          for (int oc = 0; oc < 64; ++oc) { s0 += wp0[oc * 125]; s1 += wp1[oc * 125]; }
          v0 = s0; v1 = s1;
        }
      }
      ((unsigned*)Btab)[(abc * 64 + l) * 4 + half] =
          (unsigned)f2bf(v0) | ((unsigned)f2bf(v1) << 16);
      if (abc == 0 && t == 0) {
        float bs = 0.f;
        for (int o = 0; o < 64; ++o) bs += bias[o];
        wsf[4096] = bs;
      }
    }
    return;
  }

  int tn = b >> 4, q = b & 15;    // plane q <-> dpad q+1, real d = q
  ushort_t* plane = xT + (size_t)(tn * 16 + q) * PLANE_US;
  const float* xb = x + (size_t)tn * NSTRIDE + q * 1024;

  for (int cc = 0; cc < 4; ++cc) {
    // ---- stage fp32: rows h = 8cc-1+h8 (h=-1 only cc=0,h8=0)
    for (int j = 0; j < 4; ++j) {
      int s2 = t + 576 * j;
      if (s2 < 2048) {
        int wq = s2 & 7, h8 = (s2 >> 3) & 7, ic = s2 >> 6;
        int h = 8 * cc - 1 + h8;
        if (h >= 0) {
          float4 v = *(const float4*)&xb[(size_t)ic * CHSTR + h * 32 + wq * 4];
          float* L = lb + ic * 264 + h8 * 33 + wq * 4;
          L[0] = v.x; L[1] = v.y; L[2] = v.z; L[3] = v.w;
        }
      }
    }
    __syncthreads();
    // ---- emit bf16 rows 8cc..8cc+7 (row 0 = h=-1 -> zeros; wslot 0,33 -> zeros)
    for (int j = 0; j < 2; ++j) {
      int s = t + 576 * j;
      if (s < 1088) {
        int icq = s & 3, qq = s >> 2;
        int wslot = qq % 34, r8 = qq / 34;
        int row = 8 * cc + r8;
        ushort_t o[8];
#pragma unroll
        for (int jj = 0; jj < 8; ++jj) o[jj] = 0;
        if (wslot >= 1 && wslot <= 32 && row > 0) {
          int w2 = wslot - 1;
#pragma unroll
          for (int jj = 0; jj < 8; ++jj)
            o[jj] = f2bf(lb[(8 * icq + jj) * 264 + r8 * 33 + w2]);
        }
        uint4 pk;
        pk.x = (unsigned)o[0] | ((unsigned)o[1] << 16);
        pk.y = (unsigned)o[2] | ((unsigned)o[3] << 16);
        pk.z = (unsigned)o[4] | ((unsigned)o[5] << 16);
        pk.w = (unsigned)o[6] | ((unsigned)o[7] << 16);
        *(uint4*)&plane[(size_t)row * ROW_US + wslot * 32 + icq * 8] = pk;
      }
    }
    __syncthreads();
  }
}

// ---------------- fused MFMA conv + 6^3 pool (R11 core + T1/T5) ---------
// 400 blocks; decode: xcd = blk&7 owns images {2*xcd, 2*xcd+1} (L2 affinity).
__global__ __launch_bounds__(576, 7) void conv_mfma6(const ushort_t* __restrict__ xT,
                                                     const ushort_t* __restrict__ Btab,
                                                     const float* __restrict__ wsf,
                                                     float* __restrict__ out) {
  __shared__ __align__(16) char smem[35328];
  ushort_t* As0 = (ushort_t*)smem;                 // 17408 B (8r x 34c x 32ic)
  ushort_t* As1 = (ushort_t*)(smem + 17408);       // 17408 B
  float* ytile  = (float*)smem;                    // overlays dead A-bufs
  float* red    = (float*)(smem + 34816);          // 480 B

  int blk = blockIdx.x;
  // T1: round-robin dispatch -> blk&7 = XCD. Each XCD gets 2 whole images.
  int xcd = blk & 7;
  int j = blk >> 3;                 // 0..49
  int n = 2 * xcd + (j >= 25 ? 1 : 0);
  int cell = (j >= 25) ? j - 25 : j;
  int OD = cell / 5, OH2 = cell % 5;

  int t = threadIdx.x;
  int wv = t >> 6, l = t & 63;
  int mdl = wv / 3, mhp = wv % 3;
  int tt = l & 15, g = l >> 4;

  const ushort_t* xn = xT + (size_t)n * XTN16;
  int rowoff = 6 * OH2 * (int)ROW_US;

  // ---- prologue: plane q = 3OD-1 (q=-1 iff OD==0 -> zero-fill)
  if (OD == 0) {
    for (int jj = 0; jj < 2; ++jj) {
      int s = t + 576 * jj;
      if (s < 1088) *(uint4*)&As0[s * 8] = make_uint4(0, 0, 0, 0);
    }
  } else {
    const ushort_t* slab = xn + (size_t)(3 * OD - 1) * PLANE_US + rowoff;
    uint4 v0 = *(const uint4*)(slab + (size_t)t * 8);
    uint4 v1;
    if (t < 512) v1 = *(const uint4*)(slab + (size_t)(t + 576) * 8);
    *(uint4*)&As0[t * 8] = v0;
    if (t < 512) *(uint4*)&As0[(t + 576) * 8] = v1;
  }
  __syncthreads();

  v4f acc[2][2];
#pragma unroll
  for (int m2 = 0; m2 < 2; ++m2)
#pragma unroll
    for (int wh = 0; wh < 2; ++wh) acc[m2][wh] = (v4f){0.f, 0.f, 0.f, 0.f};

  int lane_base = (2 * mhp) * ROW_US + tt * 32 + g * 8;

  for (int p = 0; p < 5; ++p) {
    // ---- T14: issue next plane's loads early (plane q = 3OD+p >= 0 always)
    uint4 v0, v1;
    if (p < 4) {
      const ushort_t* slab = xn + (size_t)(3 * OD + p) * PLANE_US + rowoff;
      v0 = *(const uint4*)(slab + (size_t)t * 8);
      if (t < 512) v1 = *(const uint4*)(slab + (size_t)(t + 576) * 8);
    }

    // ---- compute phase p (wave active if a = mdl+2-p in [0,2])
    int a = mdl + 2 - p;
    if (0 <= a && a <= 2) {
      const ushort_t* Ab = (p & 1) ? As1 : As0;
      const ushort_t* Bg = Btab + ((size_t)(a * 9) * 64 + l) * 8;
      __builtin_amdgcn_s_setprio(1);               // T5: favor MFMA waves
#pragma unroll
      for (int c = 0; c < 3; ++c) {
        v8s bv0 = *(const v8s*)(Bg + (0 * 3 + c) * 512);
        v8s bv1 = *(const v8s*)(Bg + (1 * 3 + c) * 512);
        v8s bv2 = *(const v8s*)(Bg + (2 * 3 + c) * 512);
#pragma unroll
        for (int wh = 0; wh < 2; ++wh) {
          const ushort_t* ap = Ab + lane_base + (2 - c + 16 * wh) * 32;
          v8s a0 = *(const v8s*)(ap);
          v8s a1 = *(const v8s*)(ap + 1 * ROW_US);
          v8s a2 = *(const v8s*)(ap + 2 * ROW_US);
          v8s a3 = *(const v8s*)(ap + 3 * ROW_US);
          // row j feeds (m2=0, b=2-j) and (m2=1, b=3-j)
          acc[0][wh] = __builtin_amdgcn_mfma_f32_16x16x32_bf16(a0, bv2, acc[0][wh], 0, 0, 0);
          acc[0][wh] = __builtin_amdgcn_mfma_f32_16x16x32_bf16(a1, bv1, acc[0][wh], 0, 0, 0);
          acc[0][wh] = __builtin_amdgcn_mfma_f32_16x16x32_bf16(a2, bv0, acc[0][wh], 0, 0, 0);
          acc[1][wh] = __builtin_amdgcn_mfma_f32_16x16x32_bf16(a1, bv2, acc[1][wh], 0, 0, 0);
          acc[1][wh] = __builtin_amdgcn_mfma_f32_16x16x32_bf16(a2, bv1, acc[1][wh], 0, 0, 0);
          acc[1][wh] = __builtin_amdgcn_mfma_f32_16x16x32_bf16(a3, bv0, acc[1][wh], 0, 0, 0);
        }
      }
      __builtin_amdgcn_s_setprio(0);
    }

    // ---- write next plane into other buffer, one barrier
    if (p < 4) {
      ushort_t* dst = (p & 1) ? As0 : As1;
      *(uint4*)&dst[t * 8] = v0;
      if (t < 512) *(uint4*)&dst[(t + 576) * 8] = v1;
      __syncthreads();
    }
  }

  // ---- D scatter to ytile (C/D layout verified R6)
  __syncthreads();
  if (tt < 8) {
    int td = tt & 1, th = (tt >> 1) & 1, tw = tt >> 2;
    int odl = 2 * mdl + td;
#pragma unroll
    for (int m2 = 0; m2 < 2; ++m2) {
      int ohl = 2 * (2 * mhp + m2) + th;
      float* yrow = &ytile[(odl * 12 + ohl) * 64];
#pragma unroll
      for (int wh = 0; wh < 2; ++wh)
#pragma unroll
        for (int i = 0; i < 4; ++i)
          yrow[2 * (16 * wh + 4 * g + i) + tw] = acc[m2][wh][i];
    }
  }
  __syncthreads();

  // ---- 6^3 pool: 120 threads = (odl 6, p_oh 2, OW 10)
  if (t < 120) {
    int OW = t % 10, p_oh = (t / 10) & 1, odl = t / 20;
    float m = -3.4e38f;
    for (int oh = 0; oh < 6; ++oh)
#pragma unroll
      for (int jj = 0; jj < 6; ++jj)
        m = fmaxf(m, ytile[(odl * 12 + 6 * p_oh + oh) * 64 + 6 * OW + jj]);
    red[t] = m;
  }
  __syncthreads();
  if (t < 20) {
    int OW = t % 10, p_oh = t / 10;
    float m = red[p_oh * 10 + OW];
#pragma unroll
    for (int odl = 1; odl < 6; ++odl) m = fmaxf(m, red[odl * 20 + p_oh * 10 + OW]);
    out[((n * 5 + OD) * 10 + (2 * OH2 + p_oh)) * 10 + OW] = m + wsf[4096];
  }
}

// ================= fallback: R5 verified fp32 path (tiny ws) ===========
__global__ __launch_bounds__(128) void prep2(const float* __restrict__ w,
                                             const float* __restrict__ bias,
                                             float* __restrict__ ws, int woff) {
  int i = blockIdx.x, t = threadIdx.x;
  if (t < 125) {
    const float* wp = w + (size_t)i * 64 * 125 + t;
    float v = 0.f;
#pragma unroll
    for (int o = 0; o < 64; ++o) v += wp[o * 125];
    ws[woff + i * 128 + t] = v;
  }
  if (i == 0 && t == 126) {
    float b = 0.f;
    for (int o = 0; o < 64; ++o) b += bias[o];
    ws[woff + 4096] = b;
  }
}

__global__ __launch_bounds__(256, 4) void conv_stage1(const float* __restrict__ x,
                                                      const float* __restrict__ ws,
                                                      float* part, int woff) {
  __shared__ __align__(16) float xs[170 * XSTR];
  int blk = blockIdx.x;
  int s0 = blk % 320;
  int wq = s0 & 1, hq = (s0 >> 1) & 1, dc = (s0 >> 2) % 5, n = s0 / 20;
  int t = threadIdx.x;
  int mw = t % 15, lmh = t / 15;
  int id_base = 3 * dc - 1, ih_base = 15 * hq - 1;
  int iwb = wq ? 12 : -4;
  int cb = mw + (wq ? 2 : 3);
  const float* xn = x + (size_t)n * NSTRIDE;
  const float* wsw = ws + woff;
  float acc[3][2][2][2] = {{{{0.f}}}};
  for (int phs = 0; phs < 16; ++phs) {
    for (int s = t; s < 1700; s += 256) {
      int c2 = s % 10, row = s / 10;
      int bh = row % 17, q = row / 17;
      int ad = q % 5, lic = q / 5;
      int id = id_base + ad, ih = ih_base + bh, iw = iwb + 2 * c2;
      float2 v = make_float2(0.f, 0.f);
      if ((id | ih | iw) >= 0)
        v = *(const float2*)&xn[(size_t)(phs * 2 + lic) * CHSTR + (id * 32 + ih) * 32 + iw];
      *(float2*)&xs[row * XSTR + 2 * c2] = v;
    }
    __syncthreads();
    if (t < 225) {
#pragma unroll
      for (int lic = 0; lic < 2; ++lic) {
        const float* wc = wsw + (size_t)(phs * 2 + lic) * 128;
        const float* xc = &xs[(lic * 85 + lmh) * XSTR + cb];
        float xv[5][3][3];
#pragma unroll
        for (int a = 0; a < 5; ++a)
#pragma unroll
          for (int b = 0; b < 3; ++b) {
            const float* xr = xc + (a * 17 + b) * XSTR;
            xv[a][b][0] = xr[0]; xv[a][b][1] = xr[1]; xv[a][b][2] = xr[2];
          }
#pragma unroll
        for (int kd = 0; kd < 5; ++kd) {
          constexpr int DT[5] = {0, 1, 0, 1, 0};
          constexpr int AOFF[5] = {2, 2, 1, 1, 0};
          const int dt = DT[kd], aoff = AOFF[kd];
          float wvv[25];
#pragma unroll
          for (int jj = 0; jj < 25; ++jj) wvv[jj] = wc[kd * 25 + jj];
#pragma unroll
          for (int kh = 0; kh < 5; ++kh) {
            constexpr int HT[5] = {0, 1, 0, 1, 0};
            constexpr int BOFF[5] = {2, 2, 1, 1, 0};
            const int ht = HT[kh], boff = BOFF[kh];
#pragma unroll
            for (int m = 0; m < 3; ++m) {
              const float x0 = xv[m + aoff][boff][0];
              const float x1 = xv[m + aoff][boff][1];
              const float x2 = xv[m + aoff][boff][2];
              acc[m][dt][ht][0] += x0 * wvv[kh * 5 + 4];
              acc[m][dt][ht][0] += x1 * wvv[kh * 5 + 2];
              acc[m][dt][ht][0] += x2 * wvv[kh * 5 + 0];
              acc[m][dt][ht][1] += x1 * wvv[kh * 5 + 3];
              acc[m][dt][ht][1] += x2 * wvv[kh * 5 + 1];
            }
          }
        }
      }
    }
    __syncthreads();
  }
  if (t < 225) {
    float* pb = part + (size_t)n * Y_N;
#pragma unroll
    for (int m = 0; m < 3; ++m)
#pragma unroll
      for (int dt = 0; dt < 2; ++dt)
#pragma unroll
        for (int ht = 0; ht < 2; ++ht) {
          int od_g = 6 * dc + 2 * m + dt;
          int oh_g = 30 * hq + 2 * lmh + ht;
          int ow_g = 30 * wq + 2 * mw;
          *(float2*)&pb[(od_g * 60 + oh_g) * 60 + ow_g] =
              make_float2(acc[m][dt][ht][0], acc[m][dt][ht][1]);
        }
  }
}

__global__ __launch_bounds__(256) void pool_stage2(const float* __restrict__ part,
                                                   const float* __restrict__ ws,
                                                   float* __restrict__ out, int woff) {
  __shared__ __align__(16) float buf[2160];
  __shared__ float red[240];
  int blk = blockIdx.x;
  int hc = blk % 10, dc = (blk / 10) % 5, n = blk / 50;
  int t = threadIdx.x;
  const float* pb = part + (size_t)n * Y_N;
  for (int s = t; s < 540; s += 256) {
    int row = s / 15, c4 = s % 15;
    int od = row / 6, oh = row % 6;
    size_t idx = (size_t)((6 * dc + od) * 60 + (6 * hc + oh)) * 60 + 4 * c4;
    *(float4*)&buf[row * 60 + 4 * c4] = *(const float4*)&pb[idx];
  }
  __syncthreads();
  if (t < 240) {
    int wc = t / 24, sub = t % 24;
    float m = -3.4e38f;
#pragma unroll
    for (int k = 0; k < 9; ++k) {
      int e = sub + 24 * k;
      int od = e / 36, r = e % 36;
      int oh = r / 6, ow0 = r % 6;
      m = fmaxf(m, buf[(od * 6 + oh) * 60 + 6 * wc + ow0]);
    }
    red[t] = m;
  }
  __syncthreads();
  if (t < 10) {
    float mm = -3.4e38f;
#pragma unroll
    for (int s2 = 0; s2 < 24; ++s2) mm = fmaxf(mm, red[t * 24 + s2]);
    out[((n * 5 + dc) * 10 + hc) * 10 + t] = mm + ws[woff + 4096];
  }
}

// ---------------- launch ----------------------------------------------
extern "C" void kernel_launch(void* const* d_in, const int* in_sizes, int n_in,
                              void* d_out, int out_size, void* d_ws, size_t ws_size,
                              hipStream_t stream) {
  const float* x    = (const float*)d_in[0];
  const float* w    = (const float*)d_in[1];
  const float* bias = (const float*)d_in[2];
  float* outp = (float*)d_out;

  if (ws_size >= (size_t)NEED_MFMA) {
    ushort_t* xT = (ushort_t*)d_ws;
    ushort_t* Bt = (ushort_t*)((char*)d_ws + BT_BYTE_OFF);
    float* wsf   = (float*)((char*)d_ws + WSF_BYTE_OFF);
    transpose_x<<<256 + 27, 576, 0, stream>>>(x, w, bias, xT, Bt, wsf);
    conv_mfma6<<<400, 576, 0, stream>>>(xT, Bt, wsf, outp);
    return;
  }

  // fp32 fallback (needs ~6.9 MB ws)
  float* ws = (float*)d_ws;
  const size_t need1 = ((size_t)1 * Y_TOT + 4097) * 4;
  if (ws_size >= need1) {
    int woff = Y_TOT;
    prep2<<<32, 128, 0, stream>>>(w, bias, ws, woff);
    conv_stage1<<<320, 256, 0, stream>>>(x, ws, ws, woff);
    pool_stage2<<<800, 256, 0, stream>>>(ws, ws, outp, woff);
  }
}

// Round 17
// 32.145 us; speedup vs baseline: 3.4727x; 1.0149x over previous
//
#include <hip/hip_runtime.h>

// y = convT3d(x, weight.sum(oc), stride=2, pad=2, k=5) + sum(bias); out = 6^3 stride-6 max.
// MFMA formulation (verified R6-R16, absmax 0.25): y[2m+t] = sum_{ic,abc} x[ic,m+1-abc]*w[ic,t+2abc]
//   D[16 w-cells x 8 parities] += A[cells x 32ic] * B[32ic x parities], 27 (a,b,c) chunks.
// xT: bf16 [n][q=dpad-1: 16 planes][hpad 34][wpad 34][ic 32]; dpad=0 (zero) not stored.
// R17: BOTH kernels XCD-affine (blk&7 = xcd owns images {2xcd, 2xcd+1}; model validated R16):
//   transpose WRITES image n's xT through its home L2 (2.37MB < 4MB -> stays resident), conv
//   READS it from the same L2 -> xT never round-trips HBM. Conv core R11 verbatim + T5 setprio.

typedef short v8s __attribute__((ext_vector_type(8)));
typedef float v4f __attribute__((ext_vector_type(4)));
typedef unsigned short ushort_t;

#define CHSTR 16384
#define NSTRIDE (32*CHSTR)
#define Y_N 108000
#define Y_TOT (16*Y_N)
#define XSTR 24

#define PLANE_US 36992u          // 34*34*32
#define ROW_US 1088u             // 34*32
#define XTN16 591872u            // per-n xT: 16 planes
#define BT_BYTE_OFF 18939904u    // xT = 16*XTN16*2
#define WSF_BYTE_OFF 18967552u   // +27*64*8*2
#define NEED_MFMA (18967552u + 4097u*4u)

static __device__ __forceinline__ ushort_t f2bf(float f) {
  unsigned u = __builtin_bit_cast(unsigned, f);
  unsigned r = (u + 0x7FFFu + ((u >> 16) & 1u)) >> 16;
  return (ushort_t)r;
}

// ---------------- transpose x -> xT bf16 (XCD-affine) + prep ------------
// blocks 0..255: xcd=b&7, tn=2*xcd+((b>>3)&1), q=b>>4 (bijective).
// blocks 256..282: Btab prep unit abc=b-256.
__global__ __launch_bounds__(576) void transpose_x(const float* __restrict__ x,
                                                   const float* __restrict__ wt,
                                                   const float* __restrict__ bias,
                                                   ushort_t* __restrict__ xT,
                                                   ushort_t* __restrict__ Btab,
                                                   float* __restrict__ wsf) {
  __shared__ __align__(16) float lb[32 * 264];   // [32 ic][8 h8][33 w] = 33792 B
  int b = blockIdx.x, t = threadIdx.x;

  if (b >= 256) {                 // ---- prep path (verified R10/R12 body)
    if (t < 256) {
      int abc = b - 256;
      int a = abc / 9, bb = (abc / 3) % 3, c = abc % 3;
      int half = t & 3;
      int l = t >> 2;
      int tt = l & 15, g = l >> 4;
      float v0 = 0.f, v1 = 0.f;
      if (tt < 8) {
        int td = tt & 1, th = (tt >> 1) & 1, tw = tt >> 2;
        int kd = td + 2 * a, kh = th + 2 * bb, kw = tw + 2 * c;
        if (kd < 5 && kh < 5 && kw < 5) {
          int off = kd * 25 + kh * 5 + kw;
          const float* wp0 = wt + (size_t)(8 * g + 2 * half) * 64 * 125 + off;
          const float* wp1 = wp0 + 64 * 125;
          float s0 = 0.f, s1 = 0.f;
#pragma unroll
          for (int oc = 0; oc < 64; ++oc) { s0 += wp0[oc * 125]; s1 += wp1[oc * 125]; }
          v0 = s0; v1 = s1;
        }
      }
      ((unsigned*)Btab)[(abc * 64 + l) * 4 + half] =
          (unsigned)f2bf(v0) | ((unsigned)f2bf(v1) << 16);
      if (abc == 0 && t == 0) {
        float bs = 0.f;
        for (int o = 0; o < 64; ++o) bs += bias[o];
        wsf[4096] = bs;
      }
    }
    return;
  }

  // T1 write-side: home XCD (b&7) writes its own 2 images.
  int tn = 2 * (b & 7) + ((b >> 3) & 1);
  int q  = b >> 4;                // plane q <-> dpad q+1, real d = q
  ushort_t* plane = xT + (size_t)(tn * 16 + q) * PLANE_US;
  const float* xb = x + (size_t)tn * NSTRIDE + q * 1024;

  for (int cc = 0; cc < 4; ++cc) {
    // ---- stage fp32: rows h = 8cc-1+h8 (h=-1 only cc=0,h8=0)
    for (int j = 0; j < 4; ++j) {
      int s2 = t + 576 * j;
      if (s2 < 2048) {
        int wq = s2 & 7, h8 = (s2 >> 3) & 7, ic = s2 >> 6;
        int h = 8 * cc - 1 + h8;
        if (h >= 0) {
          float4 v = *(const float4*)&xb[(size_t)ic * CHSTR + h * 32 + wq * 4];
          float* L = lb + ic * 264 + h8 * 33 + wq * 4;
          L[0] = v.x; L[1] = v.y; L[2] = v.z; L[3] = v.w;
        }
      }
    }
    __syncthreads();
    // ---- emit bf16 rows 8cc..8cc+7 (row 0 = h=-1 -> zeros; wslot 0,33 -> zeros)
    for (int j = 0; j < 2; ++j) {
      int s = t + 576 * j;
      if (s < 1088) {
        int icq = s & 3, qq = s >> 2;
        int wslot = qq % 34, r8 = qq / 34;
        int row = 8 * cc + r8;
        ushort_t o[8];
#pragma unroll
        for (int jj = 0; jj < 8; ++jj) o[jj] = 0;
        if (wslot >= 1 && wslot <= 32 && row > 0) {
          int w2 = wslot - 1;
#pragma unroll
          for (int jj = 0; jj < 8; ++jj)
            o[jj] = f2bf(lb[(8 * icq + jj) * 264 + r8 * 33 + w2]);
        }
        uint4 pk;
        pk.x = (unsigned)o[0] | ((unsigned)o[1] << 16);
        pk.y = (unsigned)o[2] | ((unsigned)o[3] << 16);
        pk.z = (unsigned)o[4] | ((unsigned)o[5] << 16);
        pk.w = (unsigned)o[6] | ((unsigned)o[7] << 16);
        *(uint4*)&plane[(size_t)row * ROW_US + wslot * 32 + icq * 8] = pk;
      }
    }
    __syncthreads();
  }
}

// ---------------- fused MFMA conv + 6^3 pool (R11 core + T1/T5) ---------
// 400 blocks; decode: xcd = blk&7 owns images {2*xcd, 2*xcd+1} (L2 affinity).
__global__ __launch_bounds__(576, 7) void conv_mfma6(const ushort_t* __restrict__ xT,
                                                     const ushort_t* __restrict__ Btab,
                                                     const float* __restrict__ wsf,
                                                     float* __restrict__ out) {
  __shared__ __align__(16) char smem[35328];
  ushort_t* As0 = (ushort_t*)smem;                 // 17408 B (8r x 34c x 32ic)
  ushort_t* As1 = (ushort_t*)(smem + 17408);       // 17408 B
  float* ytile  = (float*)smem;                    // overlays dead A-bufs
  float* red    = (float*)(smem + 34816);          // 480 B

  int blk = blockIdx.x;
  // T1: round-robin dispatch -> blk&7 = XCD. Each XCD gets 2 whole images.
  int xcd = blk & 7;
  int j = blk >> 3;                 // 0..49
  int n = 2 * xcd + (j >= 25 ? 1 : 0);
  int cell = (j >= 25) ? j - 25 : j;
  int OD = cell / 5, OH2 = cell % 5;

  int t = threadIdx.x;
  int wv = t >> 6, l = t & 63;
  int mdl = wv / 3, mhp = wv % 3;
  int tt = l & 15, g = l >> 4;

  const ushort_t* xn = xT + (size_t)n * XTN16;
  int rowoff = 6 * OH2 * (int)ROW_US;

  // ---- prologue: plane q = 3OD-1 (q=-1 iff OD==0 -> zero-fill)
  if (OD == 0) {
    for (int jj = 0; jj < 2; ++jj) {
      int s = t + 576 * jj;
      if (s < 1088) *(uint4*)&As0[s * 8] = make_uint4(0, 0, 0, 0);
    }
  } else {
    const ushort_t* slab = xn + (size_t)(3 * OD - 1) * PLANE_US + rowoff;
    uint4 v0 = *(const uint4*)(slab + (size_t)t * 8);
    uint4 v1;
    if (t < 512) v1 = *(const uint4*)(slab + (size_t)(t + 576) * 8);
    *(uint4*)&As0[t * 8] = v0;
    if (t < 512) *(uint4*)&As0[(t + 576) * 8] = v1;
  }
  __syncthreads();

  v4f acc[2][2];
#pragma unroll
  for (int m2 = 0; m2 < 2; ++m2)
#pragma unroll
    for (int wh = 0; wh < 2; ++wh) acc[m2][wh] = (v4f){0.f, 0.f, 0.f, 0.f};

  int lane_base = (2 * mhp) * ROW_US + tt * 32 + g * 8;

  for (int p = 0; p < 5; ++p) {
    // ---- T14: issue next plane's loads early (plane q = 3OD+p >= 0 always)
    uint4 v0, v1;
    if (p < 4) {
      const ushort_t* slab = xn + (size_t)(3 * OD + p) * PLANE_US + rowoff;
      v0 = *(const uint4*)(slab + (size_t)t * 8);
      if (t < 512) v1 = *(const uint4*)(slab + (size_t)(t + 576) * 8);
    }

    // ---- compute phase p (wave active if a = mdl+2-p in [0,2])
    int a = mdl + 2 - p;
    if (0 <= a && a <= 2) {
      const ushort_t* Ab = (p & 1) ? As1 : As0;
      const ushort_t* Bg = Btab + ((size_t)(a * 9) * 64 + l) * 8;
      __builtin_amdgcn_s_setprio(1);               // T5: favor MFMA waves
#pragma unroll
      for (int c = 0; c < 3; ++c) {
        v8s bv0 = *(const v8s*)(Bg + (0 * 3 + c) * 512);
        v8s bv1 = *(const v8s*)(Bg + (1 * 3 + c) * 512);
        v8s bv2 = *(const v8s*)(Bg + (2 * 3 + c) * 512);
#pragma unroll
        for (int wh = 0; wh < 2; ++wh) {
          const ushort_t* ap = Ab + lane_base + (2 - c + 16 * wh) * 32;
          v8s a0 = *(const v8s*)(ap);
          v8s a1 = *(const v8s*)(ap + 1 * ROW_US);
          v8s a2 = *(const v8s*)(ap + 2 * ROW_US);
          v8s a3 = *(const v8s*)(ap + 3 * ROW_US);
          // row j feeds (m2=0, b=2-j) and (m2=1, b=3-j)
          acc[0][wh] = __builtin_amdgcn_mfma_f32_16x16x32_bf16(a0, bv2, acc[0][wh], 0, 0, 0);
          acc[0][wh] = __builtin_amdgcn_mfma_f32_16x16x32_bf16(a1, bv1, acc[0][wh], 0, 0, 0);
          acc[0][wh] = __builtin_amdgcn_mfma_f32_16x16x32_bf16(a2, bv0, acc[0][wh], 0, 0, 0);
          acc[1][wh] = __builtin_amdgcn_mfma_f32_16x16x32_bf16(a1, bv2, acc[1][wh], 0, 0, 0);
          acc[1][wh] = __builtin_amdgcn_mfma_f32_16x16x32_bf16(a2, bv1, acc[1][wh], 0, 0, 0);
          acc[1][wh] = __builtin_amdgcn_mfma_f32_16x16x32_bf16(a3, bv0, acc[1][wh], 0, 0, 0);
        }
      }
      __builtin_amdgcn_s_setprio(0);
    }

    // ---- write next plane into other buffer, one barrier
    if (p < 4) {
      ushort_t* dst = (p & 1) ? As0 : As1;
      *(uint4*)&dst[t * 8] = v0;
      if (t < 512) *(uint4*)&dst[(t + 576) * 8] = v1;
      __syncthreads();
    }
  }

  // ---- D scatter to ytile (C/D layout verified R6)
  __syncthreads();
  if (tt < 8) {
    int td = tt & 1, th = (tt >> 1) & 1, tw = tt >> 2;
    int odl = 2 * mdl + td;
#pragma unroll
    for (int m2 = 0; m2 < 2; ++m2) {
      int ohl = 2 * (2 * mhp + m2) + th;
      float* yrow = &ytile[(odl * 12 + ohl) * 64];
#pragma unroll
      for (int wh = 0; wh < 2; ++wh)
#pragma unroll
        for (int i = 0; i < 4; ++i)
          yrow[2 * (16 * wh + 4 * g + i) + tw] = acc[m2][wh][i];
    }
  }
  __syncthreads();

  // ---- 6^3 pool: 120 threads = (odl 6, p_oh 2, OW 10)
  if (t < 120) {
    int OW = t % 10, p_oh = (t / 10) & 1, odl = t / 20;
    float m = -3.4e38f;
    for (int oh = 0; oh < 6; ++oh)
#pragma unroll
      for (int jj = 0; jj < 6; ++jj)
        m = fmaxf(m, ytile[(odl * 12 + 6 * p_oh + oh) * 64 + 6 * OW + jj]);
    red[t] = m;
  }
  __syncthreads();
  if (t < 20) {
    int OW = t % 10, p_oh = t / 10;
    float m = red[p_oh * 10 + OW];
#pragma unroll
    for (int odl = 1; odl < 6; ++odl) m = fmaxf(m, red[odl * 20 + p_oh * 10 + OW]);
    out[((n * 5 + OD) * 10 + (2 * OH2 + p_oh)) * 10 + OW] = m + wsf[4096];
  }
}

// ================= fallback: R5 verified fp32 path (tiny ws) ===========
__global__ __launch_bounds__(128) void prep2(const float* __restrict__ w,
                                             const float* __restrict__ bias,
                                             float* __restrict__ ws, int woff) {
  int i = blockIdx.x, t = threadIdx.x;
  if (t < 125) {
    const float* wp = w + (size_t)i * 64 * 125 + t;
    float v = 0.f;
#pragma unroll
    for (int o = 0; o < 64; ++o) v += wp[o * 125];
    ws[woff + i * 128 + t] = v;
  }
  if (i == 0 && t == 126) {
    float b = 0.f;
    for (int o = 0; o < 64; ++o) b += bias[o];
    ws[woff + 4096] = b;
  }
}

__global__ __launch_bounds__(256, 4) void conv_stage1(const float* __restrict__ x,
                                                      const float* __restrict__ ws,
                                                      float* part, int woff) {
  __shared__ __align__(16) float xs[170 * XSTR];
  int blk = blockIdx.x;
  int s0 = blk % 320;
  int wq = s0 & 1, hq = (s0 >> 1) & 1, dc = (s0 >> 2) % 5, n = s0 / 20;
  int t = threadIdx.x;
  int mw = t % 15, lmh = t / 15;
  int id_base = 3 * dc - 1, ih_base = 15 * hq - 1;
  int iwb = wq ? 12 : -4;
  int cb = mw + (wq ? 2 : 3);
  const float* xn = x + (size_t)n * NSTRIDE;
  const float* wsw = ws + woff;
  float acc[3][2][2][2] = {{{{0.f}}}};
  for (int phs = 0; phs < 16; ++phs) {
    for (int s = t; s < 1700; s += 256) {
      int c2 = s % 10, row = s / 10;
      int bh = row % 17, q = row / 17;
      int ad = q % 5, lic = q / 5;
      int id = id_base + ad, ih = ih_base + bh, iw = iwb + 2 * c2;
      float2 v = make_float2(0.f, 0.f);
      if ((id | ih | iw) >= 0)
        v = *(const float2*)&xn[(size_t)(phs * 2 + lic) * CHSTR + (id * 32 + ih) * 32 + iw];
      *(float2*)&xs[row * XSTR + 2 * c2] = v;
    }
    __syncthreads();
    if (t < 225) {
#pragma unroll
      for (int lic = 0; lic < 2; ++lic) {
        const float* wc = wsw + (size_t)(phs * 2 + lic) * 128;
        const float* xc = &xs[(lic * 85 + lmh) * XSTR + cb];
        float xv[5][3][3];
#pragma unroll
        for (int a = 0; a < 5; ++a)
#pragma unroll
          for (int b = 0; b < 3; ++b) {
            const float* xr = xc + (a * 17 + b) * XSTR;
            xv[a][b][0] = xr[0]; xv[a][b][1] = xr[1]; xv[a][b][2] = xr[2];
          }
#pragma unroll
        for (int kd = 0; kd < 5; ++kd) {
          constexpr int DT[5] = {0, 1, 0, 1, 0};
          constexpr int AOFF[5] = {2, 2, 1, 1, 0};
          const int dt = DT[kd], aoff = AOFF[kd];
          float wvv[25];
#pragma unroll
          for (int jj = 0; jj < 25; ++jj) wvv[jj] = wc[kd * 25 + jj];
#pragma unroll
          for (int kh = 0; kh < 5; ++kh) {
            constexpr int HT[5] = {0, 1, 0, 1, 0};
            constexpr int BOFF[5] = {2, 2, 1, 1, 0};
            const int ht = HT[kh], boff = BOFF[kh];
#pragma unroll
            for (int m = 0; m < 3; ++m) {
              const float x0 = xv[m + aoff][boff][0];
              const float x1 = xv[m + aoff][boff][1];
              const float x2 = xv[m + aoff][boff][2];
              acc[m][dt][ht][0] += x0 * wvv[kh * 5 + 4];
              acc[m][dt][ht][0] += x1 * wvv[kh * 5 + 2];
              acc[m][dt][ht][0] += x2 * wvv[kh * 5 + 0];
              acc[m][dt][ht][1] += x1 * wvv[kh * 5 + 3];
              acc[m][dt][ht][1] += x2 * wvv[kh * 5 + 1];
            }
          }
        }
      }
    }
    __syncthreads();
  }
  if (t < 225) {
    float* pb = part + (size_t)n * Y_N;
#pragma unroll
    for (int m = 0; m < 3; ++m)
#pragma unroll
      for (int dt = 0; dt < 2; ++dt)
#pragma unroll
        for (int ht = 0; ht < 2; ++ht) {
          int od_g = 6 * dc + 2 * m + dt;
          int oh_g = 30 * hq + 2 * lmh + ht;
          int ow_g = 30 * wq + 2 * mw;
          *(float2*)&pb[(od_g * 60 + oh_g) * 60 + ow_g] =
              make_float2(acc[m][dt][ht][0], acc[m][dt][ht][1]);
        }
  }
}

__global__ __launch_bounds__(256) void pool_stage2(const float* __restrict__ part,
                                                   const float* __restrict__ ws,
                                                   float* __restrict__ out, int woff) {
  __shared__ __align__(16) float buf[2160];
  __shared__ float red[240];
  int blk = blockIdx.x;
  int hc = blk % 10, dc = (blk / 10) % 5, n = blk / 50;
  int t = threadIdx.x;
  const float* pb = part + (size_t)n * Y_N;
  for (int s = t; s < 540; s += 256) {
    int row = s / 15, c4 = s % 15;
    int od = row / 6, oh = row % 6;
    size_t idx = (size_t)((6 * dc + od) * 60 + (6 * hc + oh)) * 60 + 4 * c4;
    *(float4*)&buf[row * 60 + 4 * c4] = *(const float4*)&pb[idx];
  }
  __syncthreads();
  if (t < 240) {
    int wc = t / 24, sub = t % 24;
    float m = -3.4e38f;
#pragma unroll
    for (int k = 0; k < 9; ++k) {
      int e = sub + 24 * k;
      int od = e / 36, r = e % 36;
      int oh = r / 6, ow0 = r % 6;
      m = fmaxf(m, buf[(od * 6 + oh) * 60 + 6 * wc + ow0]);
    }
    red[t] = m;
  }
  __syncthreads();
  if (t < 10) {
    float mm = -3.4e38f;
#pragma unroll
    for (int s2 = 0; s2 < 24; ++s2) mm = fmaxf(mm, red[t * 24 + s2]);
    out[((n * 5 + dc) * 10 + hc) * 10 + t] = mm + ws[woff + 4096];
  }
}

// ---------------- launch ----------------------------------------------
extern "C" void kernel_launch(void* const* d_in, const int* in_sizes, int n_in,
                              void* d_out, int out_size, void* d_ws, size_t ws_size,
                              hipStream_t stream) {
  const float* x    = (const float*)d_in[0];
  const float* w    = (const float*)d_in[1];
  const float* bias = (const float*)d_in[2];
  float* outp = (float*)d_out;

  if (ws_size >= (size_t)NEED_MFMA) {
    ushort_t* xT = (ushort_t*)d_ws;
    ushort_t* Bt = (ushort_t*)((char*)d_ws + BT_BYTE_OFF);
    float* wsf   = (float*)((char*)d_ws + WSF_BYTE_OFF);
    transpose_x<<<256 + 27, 576, 0, stream>>>(x, w, bias, xT, Bt, wsf);
    conv_mfma6<<<400, 576, 0, stream>>>(xT, Bt, wsf, outp);
    return;
  }

  // fp32 fallback (needs ~6.9 MB ws)
  float* ws = (float*)d_ws;
  const size_t need1 = ((size_t)1 * Y_TOT + 4097) * 4;
  if (ws_size >= need1) {
    int woff = Y_TOT;
    prep2<<<32, 128, 0, stream>>>(w, bias, ws, woff);
    conv_stage1<<<320, 256, 0, stream>>>(x, ws, ws, woff);
    pool_stage2<<<800, 256, 0, stream>>>(ws, ws, outp, woff);
  }
}